// Round 1
// baseline (829.200 us; speedup 1.0000x reference)
//
#include <hip/hip_runtime.h>
#include <math.h>

// Problem constants
constexpr int NB = 4;
constexpr int NS = 2048;
constexpr int ND = 512;
constexpr int NH = 8;
constexpr int NDK = 64;
constexpr int NM = NB * NS;      // 8192 rows
constexpr int NHD = NH * NDK;    // 512
constexpr float SCALE = 0.125f;  // 1/sqrt(64)
constexpr float EPS = 1e-8f;

// ws layout (floats): q | k | v | ctx, each NM*NHD = 4,194,304 floats (16 MB)
constexpr size_t TEN = (size_t)NM * NHD;

// ---------------------------------------------------------------------------
// Kernel 1: QKV projection. X[8192,512] @ W[512,512] + b -> ws in [B,H,S,DK].
// 128x128 tile, TK=8, 256 threads (16x16), 8x8 per thread (2x2 of 4x4).
// ---------------------------------------------------------------------------
__global__ __launch_bounds__(256) void proj_qkv(
    const float* __restrict__ X,
    const float* __restrict__ Wq, const float* __restrict__ bq,
    const float* __restrict__ Wk, const float* __restrict__ bk,
    const float* __restrict__ Wv, const float* __restrict__ bv,
    float* __restrict__ ws)
{
    const int z = blockIdx.z;
    const float* W    = (z == 0) ? Wq : (z == 1) ? Wk : Wv;
    const float* bias = (z == 0) ? bq : (z == 1) ? bk : bv;
    float* out = ws + (size_t)z * TEN;

    __shared__ float As[8][128];   // [k][m]
    __shared__ float Bs[8][128];   // [k][n]

    const int tx = threadIdx.x, ty = threadIdx.y;
    const int t  = ty * 16 + tx;
    const int m0 = blockIdx.y * 128;
    const int n0 = blockIdx.x * 128;

    float acc[2][2][4][4] = {};

    const int arow = t >> 1, ak = (t & 1) * 4;
    const int brow = t >> 5, bn = (t & 31) * 4;

    for (int kt = 0; kt < ND / 8; ++kt) {
        float4 av = *(const float4*)&X[(size_t)(m0 + arow) * ND + kt * 8 + ak];
        float4 bv4 = *(const float4*)&W[(size_t)(kt * 8 + brow) * NHD + n0 + bn];
        As[ak + 0][arow] = av.x;
        As[ak + 1][arow] = av.y;
        As[ak + 2][arow] = av.z;
        As[ak + 3][arow] = av.w;
        *(float4*)&Bs[brow][bn] = bv4;
        __syncthreads();
#pragma unroll
        for (int k = 0; k < 8; ++k) {
            float4 a0 = *(const float4*)&As[k][ty * 4];
            float4 a1 = *(const float4*)&As[k][64 + ty * 4];
            float4 b0 = *(const float4*)&Bs[k][tx * 4];
            float4 b1 = *(const float4*)&Bs[k][64 + tx * 4];
            float a[2][4] = {{a0.x, a0.y, a0.z, a0.w}, {a1.x, a1.y, a1.z, a1.w}};
            float bb[2][4] = {{b0.x, b0.y, b0.z, b0.w}, {b1.x, b1.y, b1.z, b1.w}};
#pragma unroll
            for (int rg = 0; rg < 2; ++rg)
#pragma unroll
                for (int cg = 0; cg < 2; ++cg)
#pragma unroll
                    for (int i = 0; i < 4; ++i)
#pragma unroll
                        for (int j = 0; j < 4; ++j)
                            acc[rg][cg][i][j] += a[rg][i] * bb[cg][j];
        }
        __syncthreads();
    }

#pragma unroll
    for (int rg = 0; rg < 2; ++rg)
#pragma unroll
        for (int i = 0; i < 4; ++i) {
            int m = m0 + rg * 64 + ty * 4 + i;
            int b = m >> 11, s = m & (NS - 1);
#pragma unroll
            for (int cg = 0; cg < 2; ++cg) {
                int n = n0 + cg * 64 + tx * 4;
                int h = n >> 6, dk = n & (NDK - 1);
                float4 bi = *(const float4*)&bias[n];
                float4 v;
                v.x = acc[rg][cg][i][0] + bi.x;
                v.y = acc[rg][cg][i][1] + bi.y;
                v.z = acc[rg][cg][i][2] + bi.z;
                v.w = acc[rg][cg][i][3] + bi.w;
                *(float4*)&out[((size_t)(b * NH + h) * NS + s) * NDK + dk] = v;
            }
        }
}

// ---------------------------------------------------------------------------
// Kernel 2: attention. One block = 64 queries of one (b,h). Loop key tiles
// of 64. No max-subtraction (matches reference; values bounded in fp32).
// ---------------------------------------------------------------------------
__global__ __launch_bounds__(256) void attn(
    const float* __restrict__ ws, const float* __restrict__ mask,
    float* __restrict__ ctx_out)
{
    const float* qw = ws;
    const float* kw = ws + TEN;
    const float* vw = ws + 2 * TEN;

    const int bh = blockIdx.y;            // 0..31
    const int b = bh >> 3;
    const int q0 = blockIdx.x * 64;
    const size_t base = (size_t)bh * NS * NDK;

    __shared__ float Qs[64][68];   // [dk][q]
    __shared__ float Ks[64][68];   // [dk][key]
    __shared__ float Ps[64][68];   // [key][q]
    __shared__ float Vs[64][68];   // [key][dk]
    __shared__ float masks[64];
    __shared__ float denoms[64];
    __shared__ float red[64][17];

    const int tx = threadIdx.x, ty = threadIdx.y;
    const int t = ty * 16 + tx;
    const int lrow = t >> 2;                 // 0..63
    const int lcol0 = (t & 3) * 16;          // 0,16,32,48

    // stage Q transposed: Qs[dk][q]
#pragma unroll
    for (int c = 0; c < 4; ++c) {
        int dk = lcol0 + 4 * c;
        float4 v = *(const float4*)&qw[base + (size_t)(q0 + lrow) * NDK + dk];
        Qs[dk + 0][lrow] = v.x;
        Qs[dk + 1][lrow] = v.y;
        Qs[dk + 2][lrow] = v.z;
        Qs[dk + 3][lrow] = v.w;
    }

    float denom_part[4] = {0.f, 0.f, 0.f, 0.f};
    float ctx_acc[4][4] = {};

    for (int kt = 0; kt < NS / 64; ++kt) {
        const int k0 = kt * 64;
        __syncthreads();   // prev PV done (and first iter: nothing)
        // stage K transposed, V natural, mask
#pragma unroll
        for (int c = 0; c < 4; ++c) {
            int dk = lcol0 + 4 * c;
            float4 kv = *(const float4*)&kw[base + (size_t)(k0 + lrow) * NDK + dk];
            Ks[dk + 0][lrow] = kv.x;
            Ks[dk + 1][lrow] = kv.y;
            Ks[dk + 2][lrow] = kv.z;
            Ks[dk + 3][lrow] = kv.w;
            float4 vv = *(const float4*)&vw[base + (size_t)(k0 + lrow) * NDK + dk];
            *(float4*)&Vs[lrow][dk] = vv;
        }
        if (t < 64) masks[t] = mask[b * NS + k0 + t];
        __syncthreads();   // staging (and Qs on first iter) visible

        // scores S[q][key] = sum_dk Qs[dk][q] * Ks[dk][key]
        float sacc[4][4] = {};
#pragma unroll 8
        for (int k = 0; k < 64; ++k) {
            float4 a = *(const float4*)&Qs[k][ty * 4];
            float4 bb = *(const float4*)&Ks[k][tx * 4];
            float av[4] = {a.x, a.y, a.z, a.w};
            float bv[4] = {bb.x, bb.y, bb.z, bb.w};
#pragma unroll
            for (int i = 0; i < 4; ++i)
#pragma unroll
                for (int j = 0; j < 4; ++j)
                    sacc[i][j] += av[i] * bv[j];
        }
        // p = exp(s*scale) * mask; accumulate denom; write P transposed
#pragma unroll
        for (int i = 0; i < 4; ++i)
#pragma unroll
            for (int j = 0; j < 4; ++j) {
                float p = __expf(sacc[i][j] * SCALE) * masks[tx * 4 + j];
                denom_part[i] += p;
                Ps[tx * 4 + j][ty * 4 + i] = p;
            }
        __syncthreads();   // P visible

        // ctx[q][dk] += sum_key Ps[key][q] * Vs[key][dk]
#pragma unroll 8
        for (int k = 0; k < 64; ++k) {
            float4 pa = *(const float4*)&Ps[k][ty * 4];
            float4 vv = *(const float4*)&Vs[k][tx * 4];
            float av[4] = {pa.x, pa.y, pa.z, pa.w};
            float bv[4] = {vv.x, vv.y, vv.z, vv.w};
#pragma unroll
            for (int i = 0; i < 4; ++i)
#pragma unroll
                for (int j = 0; j < 4; ++j)
                    ctx_acc[i][j] += av[i] * bv[j];
        }
    }

    // reduce denom across tx
    __syncthreads();
#pragma unroll
    for (int i = 0; i < 4; ++i) red[ty * 4 + i][tx] = denom_part[i];
    __syncthreads();
    if (t < 64) {
        float s = 0.f;
#pragma unroll
        for (int x = 0; x < 16; ++x) s += red[t][x];
        denoms[t] = s + EPS;
    }
    __syncthreads();

#pragma unroll
    for (int i = 0; i < 4; ++i) {
        float inv = 1.0f / denoms[ty * 4 + i];
        float4 o;
        o.x = ctx_acc[i][0] * inv;
        o.y = ctx_acc[i][1] * inv;
        o.z = ctx_acc[i][2] * inv;
        o.w = ctx_acc[i][3] * inv;
        *(float4*)&ctx_out[base + (size_t)(q0 + ty * 4 + i) * NDK + tx * 4] = o;
    }
}

// ---------------------------------------------------------------------------
// Kernel 3: output projection. ctx (gathered from [B,H,S,DK]) @ Wo + bo.
// ---------------------------------------------------------------------------
__global__ __launch_bounds__(256) void proj_out(
    const float* __restrict__ ctx, const float* __restrict__ Wo,
    const float* __restrict__ bo, float* __restrict__ out)
{
    __shared__ float As[8][128];
    __shared__ float Bs[8][128];

    const int tx = threadIdx.x, ty = threadIdx.y;
    const int t  = ty * 16 + tx;
    const int m0 = blockIdx.y * 128;
    const int n0 = blockIdx.x * 128;

    float acc[2][2][4][4] = {};

    const int arow = t >> 1, ak = (t & 1) * 4;
    const int brow = t >> 5, bn = (t & 31) * 4;
    const int am = m0 + arow;
    const int ab = am >> 11, as = am & (NS - 1);

    for (int kt = 0; kt < NHD / 8; ++kt) {
        int kk = kt * 8 + ak;
        int h = kk >> 6, dk = kk & (NDK - 1);
        float4 av = *(const float4*)&ctx[((size_t)(ab * NH + h) * NS + as) * NDK + dk];
        float4 bv4 = *(const float4*)&Wo[(size_t)(kt * 8 + brow) * ND + n0 + bn];
        As[ak + 0][arow] = av.x;
        As[ak + 1][arow] = av.y;
        As[ak + 2][arow] = av.z;
        As[ak + 3][arow] = av.w;
        *(float4*)&Bs[brow][bn] = bv4;
        __syncthreads();
#pragma unroll
        for (int k = 0; k < 8; ++k) {
            float4 a0 = *(const float4*)&As[k][ty * 4];
            float4 a1 = *(const float4*)&As[k][64 + ty * 4];
            float4 b0 = *(const float4*)&Bs[k][tx * 4];
            float4 b1 = *(const float4*)&Bs[k][64 + tx * 4];
            float a[2][4] = {{a0.x, a0.y, a0.z, a0.w}, {a1.x, a1.y, a1.z, a1.w}};
            float bb[2][4] = {{b0.x, b0.y, b0.z, b0.w}, {b1.x, b1.y, b1.z, b1.w}};
#pragma unroll
            for (int rg = 0; rg < 2; ++rg)
#pragma unroll
                for (int cg = 0; cg < 2; ++cg)
#pragma unroll
                    for (int i = 0; i < 4; ++i)
#pragma unroll
                        for (int j = 0; j < 4; ++j)
                            acc[rg][cg][i][j] += a[rg][i] * bb[cg][j];
        }
        __syncthreads();
    }

#pragma unroll
    for (int rg = 0; rg < 2; ++rg)
#pragma unroll
        for (int i = 0; i < 4; ++i) {
            int m = m0 + rg * 64 + ty * 4 + i;
#pragma unroll
            for (int cg = 0; cg < 2; ++cg) {
                int n = n0 + cg * 64 + tx * 4;
                float4 bi = *(const float4*)&bo[n];
                float4 v;
                v.x = acc[rg][cg][i][0] + bi.x;
                v.y = acc[rg][cg][i][1] + bi.y;
                v.z = acc[rg][cg][i][2] + bi.z;
                v.w = acc[rg][cg][i][3] + bi.w;
                *(float4*)&out[(size_t)m * ND + n] = v;
            }
        }
}

// ---------------------------------------------------------------------------
extern "C" void kernel_launch(void* const* d_in, const int* in_sizes, int n_in,
                              void* d_out, int out_size, void* d_ws, size_t ws_size,
                              hipStream_t stream) {
    const float* Q    = (const float*)d_in[0];
    const float* mask = (const float*)d_in[1];
    const float* Wq   = (const float*)d_in[2];
    const float* bq   = (const float*)d_in[3];
    const float* Wk   = (const float*)d_in[4];
    const float* bk   = (const float*)d_in[5];
    const float* Wv   = (const float*)d_in[6];
    const float* bv   = (const float*)d_in[7];
    const float* Wo   = (const float*)d_in[8];
    const float* bo   = (const float*)d_in[9];

    float* ws  = (float*)d_ws;
    float* ctx = ws + 3 * TEN;

    dim3 blk(16, 16);

    // q,k,v projections -> ws[0..3*TEN)
    proj_qkv<<<dim3(NHD / 128, NM / 128, 3), blk, 0, stream>>>(
        Q, Wq, bq, Wk, bk, Wv, bv, ws);

    // attention -> ctx at ws[3*TEN)
    attn<<<dim3(NS / 64, NB * NH), blk, 0, stream>>>(ws, mask, ctx);

    // output projection -> d_out
    proj_out<<<dim3(ND / 128, NM / 128), blk, 0, stream>>>(
        ctx, Wo, bo, (float*)d_out);
}

// Round 4
// 459.362 us; speedup vs baseline: 1.8051x; 1.8051x over previous
//
#include <hip/hip_runtime.h>
#include <math.h>

constexpr int NB = 4, NS = 2048, ND = 512, NH = 8, NDK = 64;
constexpr int NM = NB * NS, NHD = NH * NDK;

typedef short short8v __attribute__((ext_vector_type(8)));
typedef float f32x16v __attribute__((ext_vector_type(16)));
typedef unsigned int uint4v __attribute__((ext_vector_type(4)));

__device__ __forceinline__ unsigned short f2bf(float f) {
    unsigned u = __float_as_uint(f);
    return (unsigned short)((u + 0x7fffu + ((u >> 16) & 1u)) >> 16);
}
__device__ __forceinline__ float bf2f(unsigned short h) {
    return __uint_as_float(((unsigned)h) << 16);
}

#define MFMA32(a, b, c) __builtin_amdgcn_mfma_f32_32x32x16_bf16(a, b, c, 0, 0, 0)

// ---------------------------------------------------------------------------
// Kernel 1: QKV projection (fp32 compute). X[8192,512] @ W[512,512] + b.
// Outputs bf16 hi/lo planes [bh][s][dk] for q, k, v.
// ---------------------------------------------------------------------------
__global__ __launch_bounds__(256) void proj_qkv(
    const float* __restrict__ X,
    const float* __restrict__ Wq, const float* __restrict__ bq,
    const float* __restrict__ Wk, const float* __restrict__ bk,
    const float* __restrict__ Wv, const float* __restrict__ bv,
    unsigned short* __restrict__ qh, unsigned short* __restrict__ ql,
    unsigned short* __restrict__ kh, unsigned short* __restrict__ kl,
    unsigned short* __restrict__ vh, unsigned short* __restrict__ vl)
{
    const int z = blockIdx.z;
    const float* W    = (z == 0) ? Wq : (z == 1) ? Wk : Wv;
    const float* bias = (z == 0) ? bq : (z == 1) ? bk : bv;
    unsigned short* hp = (z == 0) ? qh : (z == 1) ? kh : vh;
    unsigned short* lp = (z == 0) ? ql : (z == 1) ? kl : vl;

    __shared__ float As[8][128];
    __shared__ float Bs[8][128];

    const int tx = threadIdx.x, ty = threadIdx.y;
    const int t  = ty * 16 + tx;
    const int m0 = blockIdx.y * 128;
    const int n0 = blockIdx.x * 128;

    float acc[2][2][4][4] = {};

    const int arow = t >> 1, ak = (t & 1) * 4;
    const int brow = t >> 5, bn = (t & 31) * 4;

    for (int kt = 0; kt < ND / 8; ++kt) {
        float4 av = *(const float4*)&X[(size_t)(m0 + arow) * ND + kt * 8 + ak];
        float4 bv4 = *(const float4*)&W[(size_t)(kt * 8 + brow) * NHD + n0 + bn];
        As[ak + 0][arow] = av.x;
        As[ak + 1][arow] = av.y;
        As[ak + 2][arow] = av.z;
        As[ak + 3][arow] = av.w;
        *(float4*)&Bs[brow][bn] = bv4;
        __syncthreads();
#pragma unroll
        for (int k = 0; k < 8; ++k) {
            float4 a0 = *(const float4*)&As[k][ty * 4];
            float4 a1 = *(const float4*)&As[k][64 + ty * 4];
            float4 b0 = *(const float4*)&Bs[k][tx * 4];
            float4 b1 = *(const float4*)&Bs[k][64 + tx * 4];
            float a[2][4] = {{a0.x, a0.y, a0.z, a0.w}, {a1.x, a1.y, a1.z, a1.w}};
            float bb[2][4] = {{b0.x, b0.y, b0.z, b0.w}, {b1.x, b1.y, b1.z, b1.w}};
#pragma unroll
            for (int rg = 0; rg < 2; ++rg)
#pragma unroll
                for (int cg = 0; cg < 2; ++cg)
#pragma unroll
                    for (int i = 0; i < 4; ++i)
#pragma unroll
                        for (int j = 0; j < 4; ++j)
                            acc[rg][cg][i][j] += a[rg][i] * bb[cg][j];
        }
        __syncthreads();
    }

#pragma unroll
    for (int rg = 0; rg < 2; ++rg)
#pragma unroll
        for (int i = 0; i < 4; ++i) {
            int m = m0 + rg * 64 + ty * 4 + i;
            int b = m >> 11, s = m & (NS - 1);
#pragma unroll
            for (int cg = 0; cg < 2; ++cg) {
                int n = n0 + cg * 64 + tx * 4;
                int h = n >> 6, dk = n & (NDK - 1);
                float4 bi = *(const float4*)&bias[n];
                float v0 = acc[rg][cg][i][0] + bi.x;
                float v1 = acc[rg][cg][i][1] + bi.y;
                float v2 = acc[rg][cg][i][2] + bi.z;
                float v3 = acc[rg][cg][i][3] + bi.w;
                unsigned short h0 = f2bf(v0), h1 = f2bf(v1), h2 = f2bf(v2), h3 = f2bf(v3);
                ushort4 hv, lv;
                hv.x = h0; hv.y = h1; hv.z = h2; hv.w = h3;
                lv.x = f2bf(v0 - bf2f(h0)); lv.y = f2bf(v1 - bf2f(h1));
                lv.z = f2bf(v2 - bf2f(h2)); lv.w = f2bf(v3 - bf2f(h3));
                size_t idx = ((size_t)(b * NH + h) * NS + s) * NDK + dk;
                *(ushort4*)&hp[idx] = hv;
                *(ushort4*)&lp[idx] = lv;
            }
        }
}

// ---------------------------------------------------------------------------
// Kernel 2: transpose V planes: [bh][s][dv] -> [bh][dv][s] (bf16 hi/lo).
// ---------------------------------------------------------------------------
__global__ __launch_bounds__(256) void vt_convert(
    const unsigned short* __restrict__ vh, const unsigned short* __restrict__ vl,
    unsigned short* __restrict__ vth, unsigned short* __restrict__ vtl)
{
    const int bh = blockIdx.y;
    const int s0 = blockIdx.x * 64;
    __shared__ unsigned short th[64][72];
    __shared__ unsigned short tl[64][72];
    const int t = threadIdx.x;
    {
        const int sl = t & 63, ch = (t >> 6) * 16;
        const unsigned short* sh = vh + ((size_t)bh * NS + s0 + sl) * NDK + ch;
        const unsigned short* sv = vl + ((size_t)bh * NS + s0 + sl) * NDK + ch;
#pragma unroll
        for (int j = 0; j < 4; ++j) {
            *(ushort4*)&th[sl][ch + 4 * j] = *(const ushort4*)(sh + 4 * j);
            *(ushort4*)&tl[sl][ch + 4 * j] = *(const ushort4*)(sv + 4 * j);
        }
    }
    __syncthreads();
    {
        const int dv = t >> 2, sc = (t & 3) * 16;
        unsigned short* dh = vth + ((size_t)bh * NDK + dv) * NS + s0 + sc;
        unsigned short* dl = vtl + ((size_t)bh * NDK + dv) * NS + s0 + sc;
#pragma unroll
        for (int j = 0; j < 4; ++j) {
            ushort4 oh, ol;
            oh.x = th[sc + 4 * j + 0][dv]; oh.y = th[sc + 4 * j + 1][dv];
            oh.z = th[sc + 4 * j + 2][dv]; oh.w = th[sc + 4 * j + 3][dv];
            ol.x = tl[sc + 4 * j + 0][dv]; ol.y = tl[sc + 4 * j + 1][dv];
            ol.z = tl[sc + 4 * j + 2][dv]; ol.w = tl[sc + 4 * j + 3][dv];
            *(ushort4*)(dh + 4 * j) = oh;
            *(ushort4*)(dl + 4 * j) = ol;
        }
    }
}

// ---------------------------------------------------------------------------
// Kernel 3: MFMA attention. Block = 128 queries of one (b,h); 4 waves, each
// owns 32 queries. Swapped QK^T (S^T = K·Q^T); P routed to the PV B-operand
// through a per-wave LDS u32-pair buffer. K/V staged via registers with
// explicit write+read XOR swizzle (no global_load_lds).
// ---------------------------------------------------------------------------
__global__ __launch_bounds__(256, 2) void attn(
    const unsigned short* __restrict__ qhp, const unsigned short* __restrict__ qlp,
    const unsigned short* __restrict__ khp, const unsigned short* __restrict__ klp,
    const unsigned short* __restrict__ vthp, const unsigned short* __restrict__ vtlp,
    const float* __restrict__ maskp, float* __restrict__ ctxT)
{
    constexpr int KH_OFF = 0, KL_OFF = 8192, VH_OFF = 16384, VL_OFF = 24576;
    constexpr int P_OFF = 32768;   // + 4 waves * (Ph[32][20] + Pl[32][20]) u32
    __shared__ __align__(16) unsigned char smem[53248];

    const int tid = threadIdx.x, lane = tid & 63, w = tid >> 6;
    const int bid = blockIdx.x;
    const int xcd = bid & 7, r0 = bid >> 3;
    const int qt = r0 & 15, bh = xcd + 8 * (r0 >> 4);
    const int b = bh >> 3;
    const int q0 = qt * 128;
    const int c = lane & 31, hi = lane >> 5;
    const int csw = (c & 7) * 16;

    unsigned* Ph = (unsigned*)(smem + P_OFF + w * 5120);
    unsigned* Pl = (unsigned*)(smem + P_OFF + w * 5120 + 2560);

    // --- reg-staged K/V: thread t handles 16B granules G1=t, G2=t+256.
    // Granule G = row r (0..63) * 8 + g. LDS position swizzle: g ^= (r&7).
    const unsigned char* kh_base = (const unsigned char*)khp + (size_t)bh * NS * 128;
    const unsigned char* kl_base = (const unsigned char*)klp + (size_t)bh * NS * 128;
    const unsigned char* vh_base = (const unsigned char*)vthp + (size_t)bh * 64 * 4096;
    const unsigned char* vl_base = (const unsigned char*)vtlp + (size_t)bh * 64 * 4096;

    const int G1 = tid, G2 = tid + 256;
    const int r1 = G1 >> 3, g1 = G1 & 7, r2 = G2 >> 3, g2 = G2 & 7;
    const int d1 = r1 * 128 + ((g1 ^ (r1 & 7)) * 16);
    const int d2 = r2 * 128 + ((g2 ^ (r2 & 7)) * 16);

    uint4v skh1, skl1, svh1, svl1, skh2, skl2, svh2, svl2;
    auto loads = [&](int kt) {
        const size_t ko = (size_t)kt * 8192;   // K tile: contiguous, byte G*16
        const size_t vo = (size_t)kt * 128;    // V tile: r*4096 + g*16 within plane
        skh1 = *(const uint4v*)(kh_base + ko + (size_t)G1 * 16);
        skh2 = *(const uint4v*)(kh_base + ko + (size_t)G2 * 16);
        skl1 = *(const uint4v*)(kl_base + ko + (size_t)G1 * 16);
        skl2 = *(const uint4v*)(kl_base + ko + (size_t)G2 * 16);
        svh1 = *(const uint4v*)(vh_base + vo + (size_t)r1 * 4096 + g1 * 16);
        svh2 = *(const uint4v*)(vh_base + vo + (size_t)r2 * 4096 + g2 * 16);
        svl1 = *(const uint4v*)(vl_base + vo + (size_t)r1 * 4096 + g1 * 16);
        svl2 = *(const uint4v*)(vl_base + vo + (size_t)r2 * 4096 + g2 * 16);
    };
    auto writes = [&]() {
        *(uint4v*)(smem + KH_OFF + d1) = skh1;
        *(uint4v*)(smem + KH_OFF + d2) = skh2;
        *(uint4v*)(smem + KL_OFF + d1) = skl1;
        *(uint4v*)(smem + KL_OFF + d2) = skl2;
        *(uint4v*)(smem + VH_OFF + d1) = svh1;
        *(uint4v*)(smem + VH_OFF + d2) = svh2;
        *(uint4v*)(smem + VL_OFF + d1) = svl1;
        *(uint4v*)(smem + VL_OFF + d2) = svl2;
    };

    // Q fragments (B operand), hoisted: col = own q, k-slot (j,hi) -> dk=16km+8hi+j
    short8v qfh[4], qfl[4];
    {
        const unsigned short* qr  = qhp + ((size_t)bh * NS + q0 + 32 * w + c) * NDK + 8 * hi;
        const unsigned short* qrl = qlp + ((size_t)bh * NS + q0 + 32 * w + c) * NDK + 8 * hi;
#pragma unroll
        for (int km = 0; km < 4; ++km) {
            qfh[km] = *(const short8v*)(qr + km * 16);
            qfl[km] = *(const short8v*)(qrl + km * 16);
        }
    }

    f32x16v acc[2];
#pragma unroll
    for (int d = 0; d < 2; ++d)
#pragma unroll
        for (int r = 0; r < 16; ++r) acc[d][r] = 0.f;
    float dsum = 0.f;

    loads(0);
    for (int kt = 0; kt < NS / 64; ++kt) {
        __syncthreads();                       // previous tile's reads done
        writes();
        if (kt + 1 < NS / 64) loads(kt + 1);   // overlap HBM latency with compute
        __syncthreads();                       // staged tile visible
#pragma unroll
        for (int kb = 0; kb < 2; ++kb) {
            // K fragments (A operand): row = key, granule 2km+hi (swizzled)
            short8v kfh[4], kfl[4];
            const int rowb = (32 * kb + c) * 128;
#pragma unroll
            for (int km = 0; km < 4; ++km) {
                const int gb = ((2 * km + hi) * 16) ^ csw;
                kfh[km] = *(const short8v*)(smem + KH_OFF + rowb + gb);
                kfl[km] = *(const short8v*)(smem + KL_OFF + rowb + gb);
            }
            f32x16v sacc;
#pragma unroll
            for (int r = 0; r < 16; ++r) sacc[r] = 0.f;
#pragma unroll
            for (int km = 0; km < 4; ++km) {
                sacc = MFMA32(kfh[km], qfh[km], sacc);
                sacc = MFMA32(kfh[km], qfl[km], sacc);
                sacc = MFMA32(kfl[km], qfh[km], sacc);
            }
            // masks for this lane's 16 keys (key = 8rr + 4hi + j), from global
            float pm[16];
#pragma unroll
            for (int rr = 0; rr < 4; ++rr) {
                float4 mv = *(const float4*)&maskp[(size_t)b * NS + kt * 64 + 32 * kb + 8 * rr + 4 * hi];
                pm[4 * rr + 0] = mv.x; pm[4 * rr + 1] = mv.y;
                pm[4 * rr + 2] = mv.z; pm[4 * rr + 3] = mv.w;
            }
            float pf[16];
#pragma unroll
            for (int r = 0; r < 16; ++r) {
                float pv = __expf(sacc[r] * 0.125f) * pm[r];
                pf[r] = pv;
                dsum += pv;
            }
            // pack P into bf16 hi/lo key-pair words
            unsigned wah[4], wbh[4], wal[4], wbl[4];
#pragma unroll
            for (int rr = 0; rr < 4; ++rr) {
                unsigned short h0 = f2bf(pf[4 * rr + 0]), h1 = f2bf(pf[4 * rr + 1]);
                unsigned short h2 = f2bf(pf[4 * rr + 2]), h3 = f2bf(pf[4 * rr + 3]);
                wah[rr] = (unsigned)h0 | ((unsigned)h1 << 16);
                wbh[rr] = (unsigned)h2 | ((unsigned)h3 << 16);
                unsigned short l0 = f2bf(pf[4 * rr + 0] - bf2f(h0));
                unsigned short l1 = f2bf(pf[4 * rr + 1] - bf2f(h1));
                unsigned short l2 = f2bf(pf[4 * rr + 2] - bf2f(h2));
                unsigned short l3 = f2bf(pf[4 * rr + 3] - bf2f(h3));
                wal[rr] = (unsigned)l0 | ((unsigned)l1 << 16);
                wbl[rr] = (unsigned)l2 | ((unsigned)l3 << 16);
            }
            // route via per-wave LDS: word widx = key-pair index within kb block
#pragma unroll
            for (int rr = 0; rr < 4; ++rr) {
                uint2 th2; th2.x = wah[rr]; th2.y = wbh[rr];
                uint2 tl2; tl2.x = wal[rr]; tl2.y = wbl[rr];
                *(uint2*)&Ph[c * 20 + 4 * rr + 2 * hi] = th2;
                *(uint2*)&Pl[c * 20 + 4 * rr + 2 * hi] = tl2;
            }
            asm volatile("s_waitcnt lgkmcnt(0)" ::: "memory");
            __builtin_amdgcn_sched_barrier(0);
#pragma unroll
            for (int pc2 = 0; pc2 < 2; ++pc2) {
                const int pc = 2 * kb + pc2;
                // B fragment: keys 16*pc2 + 8*hi + 0..7 -> widx 8*pc2+4*hi..+3
                uint4v th4 = *(const uint4v*)&Ph[c * 20 + 8 * pc2 + 4 * hi];
                uint4v tl4 = *(const uint4v*)&Pl[c * 20 + 8 * pc2 + 4 * hi];
                short8v pfh = __builtin_bit_cast(short8v, th4);
                short8v pfl = __builtin_bit_cast(short8v, tl4);
                const int vgb = ((2 * pc + hi) * 16) ^ csw;
#pragma unroll
                for (int d = 0; d < 2; ++d) {
                    const int vrow = (32 * d + c) * 128;
                    short8v vfh = *(const short8v*)(smem + VH_OFF + vrow + vgb);
                    short8v vfl = *(const short8v*)(smem + VL_OFF + vrow + vgb);
                    acc[d] = MFMA32(vfh, pfh, acc[d]);
                    acc[d] = MFMA32(vfh, pfl, acc[d]);
                    acc[d] = MFMA32(vfl, pfh, acc[d]);
                }
            }
        }
    }

    dsum += __shfl_xor(dsum, 32);
    const float inv = 1.0f / (dsum + 1e-8f);
    float* orow = ctxT + (size_t)bh * 64 * NS + q0 + 32 * w + c;
#pragma unroll
    for (int d = 0; d < 2; ++d)
#pragma unroll
        for (int r = 0; r < 16; ++r) {
            const int dv = 32 * d + (r & 3) + 8 * (r >> 2) + 4 * hi;
            orow[(size_t)dv * NS] = acc[d][r] * inv;
        }
}

// ---------------------------------------------------------------------------
// Kernel 4: output projection (fp32). A gathered from ctx^T [bh][dv][s].
// ---------------------------------------------------------------------------
__global__ __launch_bounds__(256) void proj_out(
    const float* __restrict__ ctxT, const float* __restrict__ Wo,
    const float* __restrict__ bo, float* __restrict__ out)
{
    __shared__ float As[8][128];
    __shared__ float Bs[8][128];

    const int tx = threadIdx.x, ty = threadIdx.y;
    const int t  = ty * 16 + tx;
    const int m0 = blockIdx.y * 128;
    const int n0 = blockIdx.x * 128;

    float acc[2][2][4][4] = {};

    const int kk = t >> 5, m4 = (t & 31) * 4;     // A: k-row, 4 m-columns
    const int brow = t >> 5, bn = (t & 31) * 4;   // B
    const int ab = m0 >> 11, s0 = m0 & (NS - 1);

    for (int kt = 0; kt < NHD / 8; ++kt) {
        int kg = kt * 8 + kk;
        int h = kg >> 6, dv = kg & 63;
        float4 av = *(const float4*)&ctxT[((size_t)(ab * NH + h) * NDK + dv) * NS + s0 + m4];
        float4 bv4 = *(const float4*)&Wo[(size_t)(kt * 8 + brow) * ND + n0 + bn];
        *(float4*)&As[kk][m4] = av;
        *(float4*)&Bs[brow][bn] = bv4;
        __syncthreads();
#pragma unroll
        for (int k = 0; k < 8; ++k) {
            float4 a0 = *(const float4*)&As[k][ty * 4];
            float4 a1 = *(const float4*)&As[k][64 + ty * 4];
            float4 b0 = *(const float4*)&Bs[k][tx * 4];
            float4 b1 = *(const float4*)&Bs[k][64 + tx * 4];
            float a[2][4] = {{a0.x, a0.y, a0.z, a0.w}, {a1.x, a1.y, a1.z, a1.w}};
            float bb[2][4] = {{b0.x, b0.y, b0.z, b0.w}, {b1.x, b1.y, b1.z, b1.w}};
#pragma unroll
            for (int rg = 0; rg < 2; ++rg)
#pragma unroll
                for (int cg = 0; cg < 2; ++cg)
#pragma unroll
                    for (int i = 0; i < 4; ++i)
#pragma unroll
                        for (int j = 0; j < 4; ++j)
                            acc[rg][cg][i][j] += a[rg][i] * bb[cg][j];
        }
        __syncthreads();
    }

#pragma unroll
    for (int rg = 0; rg < 2; ++rg)
#pragma unroll
        for (int i = 0; i < 4; ++i) {
            int m = m0 + rg * 64 + ty * 4 + i;
#pragma unroll
            for (int cg = 0; cg < 2; ++cg) {
                int n = n0 + cg * 64 + tx * 4;
                float4 bi = *(const float4*)&bo[n];
                float4 v;
                v.x = acc[rg][cg][i][0] + bi.x;
                v.y = acc[rg][cg][i][1] + bi.y;
                v.z = acc[rg][cg][i][2] + bi.z;
                v.w = acc[rg][cg][i][3] + bi.w;
                *(float4*)&out[(size_t)m * ND + n] = v;
            }
        }
}

// ---------------------------------------------------------------------------
extern "C" void kernel_launch(void* const* d_in, const int* in_sizes, int n_in,
                              void* d_out, int out_size, void* d_ws, size_t ws_size,
                              hipStream_t stream) {
    const float* Q    = (const float*)d_in[0];
    const float* mask = (const float*)d_in[1];
    const float* Wq   = (const float*)d_in[2];
    const float* bq   = (const float*)d_in[3];
    const float* Wk   = (const float*)d_in[4];
    const float* bk   = (const float*)d_in[5];
    const float* Wv   = (const float*)d_in[6];
    const float* bv   = (const float*)d_in[7];
    const float* Wo   = (const float*)d_in[8];
    const float* bo   = (const float*)d_in[9];

    unsigned char* W = (unsigned char*)d_ws;
    // ws layout (bytes): bf16 planes, each 8 MB
    unsigned short* qh  = (unsigned short*)(W + 0);
    unsigned short* ql  = (unsigned short*)(W + 8388608);
    unsigned short* kh  = (unsigned short*)(W + 16777216);
    unsigned short* kl  = (unsigned short*)(W + 25165824);
    unsigned short* vh  = (unsigned short*)(W + 33554432);
    unsigned short* vl  = (unsigned short*)(W + 41943040);
    unsigned short* vth = (unsigned short*)(W + 50331648);
    unsigned short* vtl = (unsigned short*)(W + 58720256);
    float* ctxT = (float*)(W + 33554432);   // aliases vh/vl (dead after vt_convert)

    proj_qkv<<<dim3(NHD / 128, NM / 128, 3), dim3(16, 16), 0, stream>>>(
        Q, Wq, bq, Wk, bk, Wv, bv, qh, ql, kh, kl, vh, vl);

    vt_convert<<<dim3(NS / 64, NB * NH), 256, 0, stream>>>(vh, vl, vth, vtl);

    attn<<<512, 256, 0, stream>>>(qh, ql, kh, kl, vth, vtl, mask, ctxT);

    proj_out<<<dim3(ND / 128, NM / 128), dim3(16, 16), 0, stream>>>(
        ctxT, Wo, bo, (float*)d_out);
}

// Round 6
// 279.352 us; speedup vs baseline: 2.9683x; 1.6444x over previous
//
#include <hip/hip_runtime.h>
#include <math.h>

constexpr int NB = 4, NS = 2048, ND = 512, NH = 8, NDK = 64;
constexpr int NM = NB * NS, NHD = NH * NDK;

typedef short short8v __attribute__((ext_vector_type(8)));
typedef float f32x16v __attribute__((ext_vector_type(16)));
typedef unsigned int uint4v __attribute__((ext_vector_type(4)));

__device__ __forceinline__ unsigned short f2bf(float f) {
    unsigned u = __float_as_uint(f);
    return (unsigned short)((u + 0x7fffu + ((u >> 16) & 1u)) >> 16);
}
__device__ __forceinline__ float bf2f(unsigned short h) {
    return __uint_as_float(((unsigned)h) << 16);
}

#define MFMA32(a, b, c) __builtin_amdgcn_mfma_f32_32x32x16_bf16(a, b, c, 0, 0, 0)

// ---------------------------------------------------------------------------
// split_x: X fp32 [8192*512] -> Xh, Xl bf16 planes.
// ---------------------------------------------------------------------------
__global__ __launch_bounds__(256) void split_x(
    const float* __restrict__ X, unsigned short* __restrict__ xh,
    unsigned short* __restrict__ xl)
{
    const size_t base = ((size_t)blockIdx.x * 256 + threadIdx.x) * 16;
#pragma unroll
    for (int j = 0; j < 4; ++j) {
        float4 v = *(const float4*)&X[base + 4 * j];
        ushort4 h, l;
        h.x = f2bf(v.x); h.y = f2bf(v.y); h.z = f2bf(v.z); h.w = f2bf(v.w);
        l.x = f2bf(v.x - bf2f(h.x)); l.y = f2bf(v.y - bf2f(h.y));
        l.z = f2bf(v.z - bf2f(h.z)); l.w = f2bf(v.w - bf2f(h.w));
        *(ushort4*)&xh[base + 4 * j] = h;
        *(ushort4*)&xl[base + 4 * j] = l;
    }
}

// ---------------------------------------------------------------------------
// split_wT: W fp32 [512][512] -> WTh, WTl bf16 [n][k] (transposed).
// ---------------------------------------------------------------------------
__global__ __launch_bounds__(256) void split_wT(
    const float* __restrict__ W0, const float* __restrict__ W1,
    const float* __restrict__ W2, const float* __restrict__ W3,
    unsigned short* __restrict__ wth, unsigned short* __restrict__ wtl)
{
    const int z = blockIdx.z;
    const float* W = (z == 0) ? W0 : (z == 1) ? W1 : (z == 2) ? W2 : W3;
    unsigned short* th = wth + (size_t)z * ND * ND;
    unsigned short* tl = wtl + (size_t)z * ND * ND;

    __shared__ float T[64][68];
    const int t = threadIdx.x;
    const int k0 = blockIdx.y * 64, n0 = blockIdx.x * 64;
    {
        const int r = t >> 2, c4 = (t & 3) * 16;
#pragma unroll
        for (int j = 0; j < 4; ++j)
            *(float4*)&T[r][c4 + 4 * j] = *(const float4*)&W[(size_t)(k0 + r) * ND + n0 + c4 + 4 * j];
    }
    __syncthreads();
    {
        const int r = t >> 2, c4 = (t & 3) * 16;
        unsigned short* dh = th + (size_t)(n0 + r) * ND + k0 + c4;
        unsigned short* dl = tl + (size_t)(n0 + r) * ND + k0 + c4;
#pragma unroll
        for (int j = 0; j < 4; ++j) {
            ushort4 h, l;
#pragma unroll
            for (int e = 0; e < 4; ++e) {
                float v = T[c4 + 4 * j + e][r];
                unsigned short hh = f2bf(v);
                ((unsigned short*)&h)[e] = hh;
                ((unsigned short*)&l)[e] = f2bf(v - bf2f(hh));
            }
            *(ushort4*)(dh + 4 * j) = h;
            *(ushort4*)(dl + 4 * j) = l;
        }
    }
}

// ---------------------------------------------------------------------------
// proj_qkv_mfma: C = X @ W + b via 3-term split-bf16 MFMA. 128x128 tile,
// BK=64, 4 waves (2x2). z: 0=q,1=k,2=v. Outputs [bh][s][dk] (v: hi only).
// ---------------------------------------------------------------------------
__global__ __launch_bounds__(256, 2) void proj_qkv_mfma(
    const unsigned short* __restrict__ xh, const unsigned short* __restrict__ xl,
    const unsigned short* __restrict__ wth, const unsigned short* __restrict__ wtl,
    const float* __restrict__ bq, const float* __restrict__ bk,
    const float* __restrict__ bv,
    unsigned short* __restrict__ qh, unsigned short* __restrict__ ql,
    unsigned short* __restrict__ kh, unsigned short* __restrict__ kl,
    unsigned short* __restrict__ vh)
{
    constexpr int AH = 0, AL = 16384, BH = 32768, BL = 49152;
    __shared__ __align__(16) unsigned char smem[65536];

    const int z = blockIdx.z;
    const float* bias = (z == 0) ? bq : (z == 1) ? bk : bv;
    unsigned short* hp = (z == 0) ? qh : (z == 1) ? kh : vh;
    unsigned short* lp = (z == 0) ? ql : (z == 1) ? kl : (unsigned short*)0;
    const unsigned char* bth = (const unsigned char*)(wth + (size_t)z * ND * ND);
    const unsigned char* btl = (const unsigned char*)(wtl + (size_t)z * ND * ND);

    const int tid = threadIdx.x, lane = tid & 63, w = tid >> 6;
    const int wm = w >> 1, wn = w & 1;
    const int c = lane & 31, hi = lane >> 5;
    const int m0 = blockIdx.y * 128, n0 = blockIdx.x * 128;

    const unsigned char* ah_base = (const unsigned char*)xh;
    const unsigned char* al_base = (const unsigned char*)xl;

    int rr[4], gg[4], dd[4];
#pragma unroll
    for (int i = 0; i < 4; ++i) {
        int G = tid + 256 * i;
        rr[i] = G >> 3; gg[i] = G & 7;
        dd[i] = rr[i] * 128 + ((gg[i] ^ (rr[i] & 7)) * 16);
    }

    uint4v sah[4], sal[4], sbh[4], sbl[4];
    auto loads = [&](int kt) {
        const int kb = kt * 128;
#pragma unroll
        for (int i = 0; i < 4; ++i) {
            const size_t arow = (size_t)(m0 + rr[i]) * 1024 + kb + gg[i] * 16;
            const size_t brow = (size_t)(n0 + rr[i]) * 1024 + kb + gg[i] * 16;
            sah[i] = *(const uint4v*)(ah_base + arow);
            sal[i] = *(const uint4v*)(al_base + arow);
            sbh[i] = *(const uint4v*)(bth + brow);
            sbl[i] = *(const uint4v*)(btl + brow);
        }
    };
    auto writes = [&]() {
#pragma unroll
        for (int i = 0; i < 4; ++i) {
            *(uint4v*)(smem + AH + dd[i]) = sah[i];
            *(uint4v*)(smem + AL + dd[i]) = sal[i];
            *(uint4v*)(smem + BH + dd[i]) = sbh[i];
            *(uint4v*)(smem + BL + dd[i]) = sbl[i];
        }
    };

    f32x16v acc[2][2];
#pragma unroll
    for (int a = 0; a < 2; ++a)
#pragma unroll
        for (int bq2 = 0; bq2 < 2; ++bq2)
#pragma unroll
            for (int r = 0; r < 16; ++r) acc[a][bq2][r] = 0.f;

    loads(0);
    for (int kt = 0; kt < ND / 64; ++kt) {
        __syncthreads();
        writes();
        if (kt + 1 < ND / 64) loads(kt + 1);
        __syncthreads();
#pragma unroll
        for (int ks = 0; ks < 4; ++ks) {
            short8v afh[2], afl[2], bfh[2], bfl[2];
#pragma unroll
            for (int ms = 0; ms < 2; ++ms) {
                const int row = wm * 64 + ms * 32 + c;
                const int gb = row * 128 + (((2 * ks + hi) ^ (c & 7)) * 16);
                afh[ms] = *(const short8v*)(smem + AH + gb);
                afl[ms] = *(const short8v*)(smem + AL + gb);
            }
#pragma unroll
            for (int ns = 0; ns < 2; ++ns) {
                const int row = wn * 64 + ns * 32 + c;
                const int gb = row * 128 + (((2 * ks + hi) ^ (c & 7)) * 16);
                bfh[ns] = *(const short8v*)(smem + BH + gb);
                bfl[ns] = *(const short8v*)(smem + BL + gb);
            }
#pragma unroll
            for (int ms = 0; ms < 2; ++ms)
#pragma unroll
                for (int ns = 0; ns < 2; ++ns) {
                    acc[ms][ns] = MFMA32(afh[ms], bfh[ns], acc[ms][ns]);
                    acc[ms][ns] = MFMA32(afh[ms], bfl[ns], acc[ms][ns]);
                    acc[ms][ns] = MFMA32(afl[ms], bfh[ns], acc[ms][ns]);
                }
        }
    }

    const int b = m0 >> 11;
    const int s_base = (m0 & (NS - 1)) + wm * 64;
#pragma unroll
    for (int ns = 0; ns < 2; ++ns) {
        const int n = n0 + wn * 64 + ns * 32 + c;
        const int h = n >> 6, dk = n & (NDK - 1);
        const float bv4 = bias[n];
        const size_t bhBase = (size_t)(b * NH + h) * NS * NDK + dk;
#pragma unroll
        for (int ms = 0; ms < 2; ++ms)
#pragma unroll
            for (int r = 0; r < 16; ++r) {
                const int s = s_base + ms * 32 + (r & 3) + 8 * (r >> 2) + 4 * hi;
                const float v = acc[ms][ns][r] + bv4;
                const unsigned short h0 = f2bf(v);
                hp[bhBase + (size_t)s * NDK] = h0;
                if (lp) lp[bhBase + (size_t)s * NDK] = f2bf(v - bf2f(h0));
            }
    }
}

// ---------------------------------------------------------------------------
// vt_convert: V hi plane [bh][s][dv] -> [bh][dv][s].
// ---------------------------------------------------------------------------
__global__ __launch_bounds__(256) void vt_convert(
    const unsigned short* __restrict__ vh, unsigned short* __restrict__ vth)
{
    const int bh = blockIdx.y;
    const int s0 = blockIdx.x * 64;
    __shared__ unsigned short th[64][72];
    const int t = threadIdx.x;
    {
        const int sl = t & 63, ch = (t >> 6) * 16;
        const unsigned short* sh = vh + ((size_t)bh * NS + s0 + sl) * NDK + ch;
#pragma unroll
        for (int j = 0; j < 4; ++j)
            *(ushort4*)&th[sl][ch + 4 * j] = *(const ushort4*)(sh + 4 * j);
    }
    __syncthreads();
    {
        const int dv = t >> 2, sc = (t & 3) * 16;
        unsigned short* dh = vth + ((size_t)bh * NDK + dv) * NS + s0 + sc;
#pragma unroll
        for (int j = 0; j < 4; ++j) {
            ushort4 oh;
            oh.x = th[sc + 4 * j + 0][dv]; oh.y = th[sc + 4 * j + 1][dv];
            oh.z = th[sc + 4 * j + 2][dv]; oh.w = th[sc + 4 * j + 3][dv];
            *(ushort4*)(dh + 4 * j) = oh;
        }
    }
}

// ---------------------------------------------------------------------------
// attn: MFMA attention; V hi-only (2-term PV). Outputs ctx^T as bf16 hi/lo
// planes [bh][dv][s] (no fp32 buffer -> no aliasing with live K planes).
// ---------------------------------------------------------------------------
__global__ __launch_bounds__(256, 2) void attn(
    const unsigned short* __restrict__ qhp, const unsigned short* __restrict__ qlp,
    const unsigned short* __restrict__ khp, const unsigned short* __restrict__ klp,
    const unsigned short* __restrict__ vthp,
    const float* __restrict__ maskp,
    unsigned short* __restrict__ cth, unsigned short* __restrict__ ctl)
{
    constexpr int KH_OFF = 0, KL_OFF = 8192, VH_OFF = 16384;
    constexpr int P_OFF = 24576;
    __shared__ __align__(16) unsigned char smem[45056];

    const int tid = threadIdx.x, lane = tid & 63, w = tid >> 6;
    const int bid = blockIdx.x;
    const int xcd = bid & 7, r0 = bid >> 3;
    const int qt = r0 & 15, bh = xcd + 8 * (r0 >> 4);
    const int b = bh >> 3;
    const int q0 = qt * 128;
    const int c = lane & 31, hi = lane >> 5;
    const int csw = (c & 7) * 16;

    unsigned* Ph = (unsigned*)(smem + P_OFF + w * 5120);
    unsigned* Pl = (unsigned*)(smem + P_OFF + w * 5120 + 2560);

    const unsigned char* kh_base = (const unsigned char*)khp + (size_t)bh * NS * 128;
    const unsigned char* kl_base = (const unsigned char*)klp + (size_t)bh * NS * 128;
    const unsigned char* vh_base = (const unsigned char*)vthp + (size_t)bh * 64 * 4096;

    const int G1 = tid, G2 = tid + 256;
    const int r1 = G1 >> 3, g1 = G1 & 7, r2 = G2 >> 3, g2 = G2 & 7;
    const int d1 = r1 * 128 + ((g1 ^ (r1 & 7)) * 16);
    const int d2 = r2 * 128 + ((g2 ^ (r2 & 7)) * 16);

    uint4v skh1, skl1, svh1, skh2, skl2, svh2;
    auto loads = [&](int kt) {
        const size_t ko = (size_t)kt * 8192;
        const size_t vo = (size_t)kt * 128;
        skh1 = *(const uint4v*)(kh_base + ko + (size_t)G1 * 16);
        skh2 = *(const uint4v*)(kh_base + ko + (size_t)G2 * 16);
        skl1 = *(const uint4v*)(kl_base + ko + (size_t)G1 * 16);
        skl2 = *(const uint4v*)(kl_base + ko + (size_t)G2 * 16);
        svh1 = *(const uint4v*)(vh_base + vo + (size_t)r1 * 4096 + g1 * 16);
        svh2 = *(const uint4v*)(vh_base + vo + (size_t)r2 * 4096 + g2 * 16);
    };
    auto writes = [&]() {
        *(uint4v*)(smem + KH_OFF + d1) = skh1;
        *(uint4v*)(smem + KH_OFF + d2) = skh2;
        *(uint4v*)(smem + KL_OFF + d1) = skl1;
        *(uint4v*)(smem + KL_OFF + d2) = skl2;
        *(uint4v*)(smem + VH_OFF + d1) = svh1;
        *(uint4v*)(smem + VH_OFF + d2) = svh2;
    };

    short8v qfh[4], qfl[4];
    {
        const unsigned short* qr  = qhp + ((size_t)bh * NS + q0 + 32 * w + c) * NDK + 8 * hi;
        const unsigned short* qrl = qlp + ((size_t)bh * NS + q0 + 32 * w + c) * NDK + 8 * hi;
#pragma unroll
        for (int km = 0; km < 4; ++km) {
            qfh[km] = *(const short8v*)(qr + km * 16);
            qfl[km] = *(const short8v*)(qrl + km * 16);
        }
    }

    f32x16v acc[2];
#pragma unroll
    for (int d = 0; d < 2; ++d)
#pragma unroll
        for (int r = 0; r < 16; ++r) acc[d][r] = 0.f;
    float dsum = 0.f;

    loads(0);
    for (int kt = 0; kt < NS / 64; ++kt) {
        __syncthreads();
        writes();
        if (kt + 1 < NS / 64) loads(kt + 1);
        __syncthreads();
#pragma unroll
        for (int kb = 0; kb < 2; ++kb) {
            short8v kfh[4], kfl[4];
            const int rowb = (32 * kb + c) * 128;
#pragma unroll
            for (int km = 0; km < 4; ++km) {
                const int gb = ((2 * km + hi) * 16) ^ csw;
                kfh[km] = *(const short8v*)(smem + KH_OFF + rowb + gb);
                kfl[km] = *(const short8v*)(smem + KL_OFF + rowb + gb);
            }
            f32x16v sacc;
#pragma unroll
            for (int r = 0; r < 16; ++r) sacc[r] = 0.f;
#pragma unroll
            for (int km = 0; km < 4; ++km) {
                sacc = MFMA32(kfh[km], qfh[km], sacc);
                sacc = MFMA32(kfh[km], qfl[km], sacc);
                sacc = MFMA32(kfl[km], qfh[km], sacc);
            }
            float pm[16];
#pragma unroll
            for (int rr2 = 0; rr2 < 4; ++rr2) {
                float4 mv = *(const float4*)&maskp[(size_t)b * NS + kt * 64 + 32 * kb + 8 * rr2 + 4 * hi];
                pm[4 * rr2 + 0] = mv.x; pm[4 * rr2 + 1] = mv.y;
                pm[4 * rr2 + 2] = mv.z; pm[4 * rr2 + 3] = mv.w;
            }
            float pf[16];
#pragma unroll
            for (int r = 0; r < 16; ++r) {
                float pv = __expf(sacc[r] * 0.125f) * pm[r];
                pf[r] = pv;
                dsum += pv;
            }
            unsigned wah[4], wbh[4], wal[4], wbl[4];
#pragma unroll
            for (int rr2 = 0; rr2 < 4; ++rr2) {
                unsigned short h0 = f2bf(pf[4 * rr2 + 0]), h1 = f2bf(pf[4 * rr2 + 1]);
                unsigned short h2 = f2bf(pf[4 * rr2 + 2]), h3 = f2bf(pf[4 * rr2 + 3]);
                wah[rr2] = (unsigned)h0 | ((unsigned)h1 << 16);
                wbh[rr2] = (unsigned)h2 | ((unsigned)h3 << 16);
                unsigned short l0 = f2bf(pf[4 * rr2 + 0] - bf2f(h0));
                unsigned short l1 = f2bf(pf[4 * rr2 + 1] - bf2f(h1));
                unsigned short l2 = f2bf(pf[4 * rr2 + 2] - bf2f(h2));
                unsigned short l3 = f2bf(pf[4 * rr2 + 3] - bf2f(h3));
                wal[rr2] = (unsigned)l0 | ((unsigned)l1 << 16);
                wbl[rr2] = (unsigned)l2 | ((unsigned)l3 << 16);
            }
#pragma unroll
            for (int rr2 = 0; rr2 < 4; ++rr2) {
                uint2 th2; th2.x = wah[rr2]; th2.y = wbh[rr2];
                uint2 tl2; tl2.x = wal[rr2]; tl2.y = wbl[rr2];
                *(uint2*)&Ph[c * 20 + 4 * rr2 + 2 * hi] = th2;
                *(uint2*)&Pl[c * 20 + 4 * rr2 + 2 * hi] = tl2;
            }
            asm volatile("s_waitcnt lgkmcnt(0)" ::: "memory");
            __builtin_amdgcn_sched_barrier(0);
#pragma unroll
            for (int pc2 = 0; pc2 < 2; ++pc2) {
                const int pc = 2 * kb + pc2;
                uint4v th4 = *(const uint4v*)&Ph[c * 20 + 8 * pc2 + 4 * hi];
                uint4v tl4 = *(const uint4v*)&Pl[c * 20 + 8 * pc2 + 4 * hi];
                short8v pfh = __builtin_bit_cast(short8v, th4);
                short8v pfl = __builtin_bit_cast(short8v, tl4);
                const int vgb = ((2 * pc + hi) * 16) ^ csw;
#pragma unroll
                for (int d = 0; d < 2; ++d) {
                    const int vrow = (32 * d + c) * 128;
                    short8v vfh = *(const short8v*)(smem + VH_OFF + vrow + vgb);
                    acc[d] = MFMA32(vfh, pfh, acc[d]);
                    acc[d] = MFMA32(vfh, pfl, acc[d]);
                }
            }
        }
    }

    dsum += __shfl_xor(dsum, 32);
    const float inv = 1.0f / (dsum + 1e-8f);
    unsigned short* ohr = cth + (size_t)bh * 64 * NS + q0 + 32 * w + c;
    unsigned short* olr = ctl + (size_t)bh * 64 * NS + q0 + 32 * w + c;
#pragma unroll
    for (int d = 0; d < 2; ++d)
#pragma unroll
        for (int r = 0; r < 16; ++r) {
            const int dv = 32 * d + (r & 3) + 8 * (r >> 2) + 4 * hi;
            const float v = acc[d][r] * inv;
            const unsigned short h0 = f2bf(v);
            ohr[(size_t)dv * NS] = h0;
            olr[(size_t)dv * NS] = f2bf(v - bf2f(h0));
        }
}

// ---------------------------------------------------------------------------
// ctx_split: bf16 planes [bh][dv][s] -> natural [b*s][h*64+dv] (hi/lo).
// ---------------------------------------------------------------------------
__global__ __launch_bounds__(256) void ctx_split(
    const unsigned short* __restrict__ cth, const unsigned short* __restrict__ ctl,
    unsigned short* __restrict__ cnh, unsigned short* __restrict__ cnl)
{
    const int bh = blockIdx.y;
    const int b = bh >> 3, h = bh & 7;
    const int s0 = blockIdx.x * 64;
    __shared__ unsigned short th[64][72];
    __shared__ unsigned short tl[64][72];
    const int t = threadIdx.x;
    {
        const int rd = t >> 2, sc = (t & 3) * 16;
        const unsigned short* sh = cth + ((size_t)bh * NDK + rd) * NS + s0 + sc;
        const unsigned short* sv = ctl + ((size_t)bh * NDK + rd) * NS + s0 + sc;
#pragma unroll
        for (int j = 0; j < 4; ++j) {
            *(ushort4*)&th[rd][sc + 4 * j] = *(const ushort4*)(sh + 4 * j);
            *(ushort4*)&tl[rd][sc + 4 * j] = *(const ushort4*)(sv + 4 * j);
        }
    }
    __syncthreads();
    {
        const int sl = t >> 2, kc = (t & 3) * 16;
        const size_t m = (size_t)b * NS + s0 + sl;
        unsigned short* dh = cnh + m * NHD + h * NDK + kc;
        unsigned short* dl = cnl + m * NHD + h * NDK + kc;
#pragma unroll
        for (int j = 0; j < 4; ++j) {
            ushort4 hh, ll;
#pragma unroll
            for (int e = 0; e < 4; ++e) {
                hh_e_assign:;
                ((unsigned short*)&hh)[e] = th[kc + 4 * j + e][sl];
                ((unsigned short*)&ll)[e] = tl[kc + 4 * j + e][sl];
            }
            *(ushort4*)(dh + 4 * j) = hh;
            *(ushort4*)(dl + 4 * j) = ll;
        }
    }
}

// ---------------------------------------------------------------------------
// proj_out_mfma: out = ctxN @ Wo + bo (3-term split MFMA), fp32 out.
// ---------------------------------------------------------------------------
__global__ __launch_bounds__(256, 2) void proj_out_mfma(
    const unsigned short* __restrict__ cnh, const unsigned short* __restrict__ cnl,
    const unsigned short* __restrict__ wth, const unsigned short* __restrict__ wtl,
    const float* __restrict__ bo, float* __restrict__ out)
{
    constexpr int AH = 0, AL = 16384, BH = 32768, BL = 49152;
    __shared__ __align__(16) unsigned char smem[65536];

    const int tid = threadIdx.x, lane = tid & 63, w = tid >> 6;
    const int wm = w >> 1, wn = w & 1;
    const int c = lane & 31, hi = lane >> 5;
    const int m0 = blockIdx.y * 128, n0 = blockIdx.x * 128;

    const unsigned char* ah_base = (const unsigned char*)cnh;
    const unsigned char* al_base = (const unsigned char*)cnl;
    const unsigned char* bth = (const unsigned char*)wth;
    const unsigned char* btl = (const unsigned char*)wtl;

    int rr[4], gg[4], dd[4];
#pragma unroll
    for (int i = 0; i < 4; ++i) {
        int G = tid + 256 * i;
        rr[i] = G >> 3; gg[i] = G & 7;
        dd[i] = rr[i] * 128 + ((gg[i] ^ (rr[i] & 7)) * 16);
    }

    uint4v sah[4], sal[4], sbh[4], sbl[4];
    auto loads = [&](int kt) {
        const int kb = kt * 128;
#pragma unroll
        for (int i = 0; i < 4; ++i) {
            const size_t arow = (size_t)(m0 + rr[i]) * 1024 + kb + gg[i] * 16;
            const size_t brow = (size_t)(n0 + rr[i]) * 1024 + kb + gg[i] * 16;
            sah[i] = *(const uint4v*)(ah_base + arow);
            sal[i] = *(const uint4v*)(al_base + arow);
            sbh[i] = *(const uint4v*)(bth + brow);
            sbl[i] = *(const uint4v*)(btl + brow);
        }
    };
    auto writes = [&]() {
#pragma unroll
        for (int i = 0; i < 4; ++i) {
            *(uint4v*)(smem + AH + dd[i]) = sah[i];
            *(uint4v*)(smem + AL + dd[i]) = sal[i];
            *(uint4v*)(smem + BH + dd[i]) = sbh[i];
            *(uint4v*)(smem + BL + dd[i]) = sbl[i];
        }
    };

    f32x16v acc[2][2];
#pragma unroll
    for (int a = 0; a < 2; ++a)
#pragma unroll
        for (int bq2 = 0; bq2 < 2; ++bq2)
#pragma unroll
            for (int r = 0; r < 16; ++r) acc[a][bq2][r] = 0.f;

    loads(0);
    for (int kt = 0; kt < NHD / 64; ++kt) {
        __syncthreads();
        writes();
        if (kt + 1 < NHD / 64) loads(kt + 1);
        __syncthreads();
#pragma unroll
        for (int ks = 0; ks < 4; ++ks) {
            short8v afh[2], afl[2], bfh[2], bfl[2];
#pragma unroll
            for (int ms = 0; ms < 2; ++ms) {
                const int row = wm * 64 + ms * 32 + c;
                const int gb = row * 128 + (((2 * ks + hi) ^ (c & 7)) * 16);
                afh[ms] = *(const short8v*)(smem + AH + gb);
                afl[ms] = *(const short8v*)(smem + AL + gb);
            }
#pragma unroll
            for (int ns = 0; ns < 2; ++ns) {
                const int row = wn * 64 + ns * 32 + c;
                const int gb = row * 128 + (((2 * ks + hi) ^ (c & 7)) * 16);
                bfh[ns] = *(const short8v*)(smem + BH + gb);
                bfl[ns] = *(const short8v*)(smem + BL + gb);
            }
#pragma unroll
            for (int ms = 0; ms < 2; ++ms)
#pragma unroll
                for (int ns = 0; ns < 2; ++ns) {
                    acc[ms][ns] = MFMA32(afh[ms], bfh[ns], acc[ms][ns]);
                    acc[ms][ns] = MFMA32(afh[ms], bfl[ns], acc[ms][ns]);
                    acc[ms][ns] = MFMA32(afl[ms], bfh[ns], acc[ms][ns]);
                }
        }
    }

#pragma unroll
    for (int ns = 0; ns < 2; ++ns) {
        const int n = n0 + wn * 64 + ns * 32 + c;
        const float bv4 = bo[n];
#pragma unroll
        for (int ms = 0; ms < 2; ++ms)
#pragma unroll
            for (int r = 0; r < 16; ++r) {
                const int m = m0 + wm * 64 + ms * 32 + (r & 3) + 8 * (r >> 2) + 4 * hi;
                out[(size_t)m * ND + n] = acc[ms][ns][r] + bv4;
            }
    }
}

// ---------------------------------------------------------------------------
extern "C" void kernel_launch(void* const* d_in, const int* in_sizes, int n_in,
                              void* d_out, int out_size, void* d_ws, size_t ws_size,
                              hipStream_t stream) {
    const float* Q    = (const float*)d_in[0];
    const float* mask = (const float*)d_in[1];
    const float* Wq   = (const float*)d_in[2];
    const float* bq   = (const float*)d_in[3];
    const float* Wk   = (const float*)d_in[4];
    const float* bk   = (const float*)d_in[5];
    const float* Wv   = (const float*)d_in[6];
    const float* bv   = (const float*)d_in[7];
    const float* Wo   = (const float*)d_in[8];
    const float* bo   = (const float*)d_in[9];

    unsigned char* W = (unsigned char*)d_ws;
    constexpr size_t MB = 1048576;
    // live-range-audited layout (no read/write overlap within any kernel):
    unsigned short* xh   = (unsigned short*)(W + 0);         // split_x .. proj_qkv
    unsigned short* xl   = (unsigned short*)(W + 8 * MB);    // split_x .. proj_qkv
    unsigned short* wtH  = (unsigned short*)(W + 16 * MB);   // split_wT .. proj_out
    unsigned short* wtL  = (unsigned short*)(W + 18 * MB);
    unsigned short* qh   = (unsigned short*)(W + 20 * MB);   // proj_qkv .. attn
    unsigned short* ql   = (unsigned short*)(W + 28 * MB);
    unsigned short* kh   = (unsigned short*)(W + 36 * MB);
    unsigned short* kl   = (unsigned short*)(W + 44 * MB);
    unsigned short* vh   = (unsigned short*)(W + 52 * MB);   // proj_qkv .. vt_convert
    unsigned short* vth  = (unsigned short*)(W + 0);         // vt_convert .. attn (over xh)
    unsigned short* cth  = (unsigned short*)(W + 8 * MB);    // attn .. ctx_split (over xl)
    unsigned short* ctl  = (unsigned short*)(W + 52 * MB);   // attn .. ctx_split (over vh)
    unsigned short* cnh  = (unsigned short*)(W + 20 * MB);   // ctx_split .. proj_out (over qh)
    unsigned short* cnl  = (unsigned short*)(W + 28 * MB);   //   (over ql)

    split_x<<<NM * ND / (256 * 16), 256, 0, stream>>>(Q, xh, xl);
    split_wT<<<dim3(8, 8, 4), 256, 0, stream>>>(Wq, Wk, Wv, Wo, wtH, wtL);

    proj_qkv_mfma<<<dim3(NHD / 128, NM / 128, 3), 256, 0, stream>>>(
        xh, xl, wtH, wtL, bq, bk, bv, qh, ql, kh, kl, vh);

    vt_convert<<<dim3(NS / 64, NB * NH), 256, 0, stream>>>(vh, vth);

    attn<<<512, 256, 0, stream>>>(qh, ql, kh, kl, vth, mask, cth, ctl);

    ctx_split<<<dim3(NS / 64, NB * NH), 256, 0, stream>>>(cth, ctl, cnh, cnl);

    proj_out_mfma<<<dim3(ND / 128, NM / 128), 256, 0, stream>>>(
        cnh, cnl, wtH + (size_t)3 * ND * ND, wtL + (size_t)3 * ND * ND,
        bo, (float*)d_out);
}

// Round 7
// 262.858 us; speedup vs baseline: 3.1546x; 1.0627x over previous
//
#include <hip/hip_runtime.h>
#include <math.h>

constexpr int NB = 4, NS = 2048, ND = 512, NH = 8, NDK = 64;
constexpr int NM = NB * NS, NHD = NH * NDK;

typedef short short8v __attribute__((ext_vector_type(8)));
typedef float f32x16v __attribute__((ext_vector_type(16)));
typedef unsigned int uint4v __attribute__((ext_vector_type(4)));

__device__ __forceinline__ unsigned short f2bf(float f) {
    unsigned u = __float_as_uint(f);
    return (unsigned short)((u + 0x7fffu + ((u >> 16) & 1u)) >> 16);
}
__device__ __forceinline__ float bf2f(unsigned short h) {
    return __uint_as_float(((unsigned)h) << 16);
}

#define MFMA32(a, b, c) __builtin_amdgcn_mfma_f32_32x32x16_bf16(a, b, c, 0, 0, 0)

// ---------------------------------------------------------------------------
// split_x: X fp32 [8192*512] -> Xh, Xl bf16 planes.
// ---------------------------------------------------------------------------
__global__ __launch_bounds__(256) void split_x(
    const float* __restrict__ X, unsigned short* __restrict__ xh,
    unsigned short* __restrict__ xl)
{
    const size_t base = ((size_t)blockIdx.x * 256 + threadIdx.x) * 16;
#pragma unroll
    for (int j = 0; j < 4; ++j) {
        float4 v = *(const float4*)&X[base + 4 * j];
        ushort4 h, l;
        h.x = f2bf(v.x); h.y = f2bf(v.y); h.z = f2bf(v.z); h.w = f2bf(v.w);
        l.x = f2bf(v.x - bf2f(h.x)); l.y = f2bf(v.y - bf2f(h.y));
        l.z = f2bf(v.z - bf2f(h.z)); l.w = f2bf(v.w - bf2f(h.w));
        *(ushort4*)&xh[base + 4 * j] = h;
        *(ushort4*)&xl[base + 4 * j] = l;
    }
}

// ---------------------------------------------------------------------------
// split_wT: W fp32 [512][512] -> WTh, WTl bf16 [n][k] (transposed).
// ---------------------------------------------------------------------------
__global__ __launch_bounds__(256) void split_wT(
    const float* __restrict__ W0, const float* __restrict__ W1,
    const float* __restrict__ W2, const float* __restrict__ W3,
    unsigned short* __restrict__ wth, unsigned short* __restrict__ wtl)
{
    const int z = blockIdx.z;
    const float* W = (z == 0) ? W0 : (z == 1) ? W1 : (z == 2) ? W2 : W3;
    unsigned short* th = wth + (size_t)z * ND * ND;
    unsigned short* tl = wtl + (size_t)z * ND * ND;

    __shared__ float T[64][68];
    const int t = threadIdx.x;
    const int k0 = blockIdx.y * 64, n0 = blockIdx.x * 64;
    {
        const int r = t >> 2, c4 = (t & 3) * 16;
#pragma unroll
        for (int j = 0; j < 4; ++j)
            *(float4*)&T[r][c4 + 4 * j] = *(const float4*)&W[(size_t)(k0 + r) * ND + n0 + c4 + 4 * j];
    }
    __syncthreads();
    {
        const int r = t >> 2, c4 = (t & 3) * 16;
        unsigned short* dh = th + (size_t)(n0 + r) * ND + k0 + c4;
        unsigned short* dl = tl + (size_t)(n0 + r) * ND + k0 + c4;
#pragma unroll
        for (int j = 0; j < 4; ++j) {
            ushort4 h, l;
#pragma unroll
            for (int e = 0; e < 4; ++e) {
                float v = T[c4 + 4 * j + e][r];
                unsigned short hh = f2bf(v);
                ((unsigned short*)&h)[e] = hh;
                ((unsigned short*)&l)[e] = f2bf(v - bf2f(hh));
            }
            *(ushort4*)(dh + 4 * j) = h;
            *(ushort4*)(dl + 4 * j) = l;
        }
    }
}

// ---------------------------------------------------------------------------
// proj_qkv_mfma: C = X @ W + b via 3-term split-bf16 MFMA. 128x128 tile,
// BK=64, 4 waves (2x2). z: 0=q,1=k,2=v. Outputs [bh][s][dk] (v: hi only).
// ---------------------------------------------------------------------------
__global__ __launch_bounds__(256, 2) void proj_qkv_mfma(
    const unsigned short* __restrict__ xh, const unsigned short* __restrict__ xl,
    const unsigned short* __restrict__ wth, const unsigned short* __restrict__ wtl,
    const float* __restrict__ bq, const float* __restrict__ bk,
    const float* __restrict__ bv,
    unsigned short* __restrict__ qh, unsigned short* __restrict__ ql,
    unsigned short* __restrict__ kh, unsigned short* __restrict__ kl,
    unsigned short* __restrict__ vh)
{
    constexpr int AH = 0, AL = 16384, BH = 32768, BL = 49152;
    __shared__ __align__(16) unsigned char smem[65536];

    const int z = blockIdx.z;
    const float* bias = (z == 0) ? bq : (z == 1) ? bk : bv;
    unsigned short* hp = (z == 0) ? qh : (z == 1) ? kh : vh;
    unsigned short* lp = (z == 0) ? ql : (z == 1) ? kl : (unsigned short*)0;
    const unsigned char* bth = (const unsigned char*)(wth + (size_t)z * ND * ND);
    const unsigned char* btl = (const unsigned char*)(wtl + (size_t)z * ND * ND);

    const int tid = threadIdx.x, lane = tid & 63, w = tid >> 6;
    const int wm = w >> 1, wn = w & 1;
    const int c = lane & 31, hi = lane >> 5;
    const int m0 = blockIdx.y * 128, n0 = blockIdx.x * 128;

    const unsigned char* ah_base = (const unsigned char*)xh;
    const unsigned char* al_base = (const unsigned char*)xl;

    int rr[4], gg[4], dd[4];
#pragma unroll
    for (int i = 0; i < 4; ++i) {
        int G = tid + 256 * i;
        rr[i] = G >> 3; gg[i] = G & 7;
        dd[i] = rr[i] * 128 + ((gg[i] ^ (rr[i] & 7)) * 16);
    }

    uint4v sah[4], sal[4], sbh[4], sbl[4];
    auto loads = [&](int kt) {
        const int kb = kt * 128;
#pragma unroll
        for (int i = 0; i < 4; ++i) {
            const size_t arow = (size_t)(m0 + rr[i]) * 1024 + kb + gg[i] * 16;
            const size_t brow = (size_t)(n0 + rr[i]) * 1024 + kb + gg[i] * 16;
            sah[i] = *(const uint4v*)(ah_base + arow);
            sal[i] = *(const uint4v*)(al_base + arow);
            sbh[i] = *(const uint4v*)(bth + brow);
            sbl[i] = *(const uint4v*)(btl + brow);
        }
    };
    auto writes = [&]() {
#pragma unroll
        for (int i = 0; i < 4; ++i) {
            *(uint4v*)(smem + AH + dd[i]) = sah[i];
            *(uint4v*)(smem + AL + dd[i]) = sal[i];
            *(uint4v*)(smem + BH + dd[i]) = sbh[i];
            *(uint4v*)(smem + BL + dd[i]) = sbl[i];
        }
    };

    f32x16v acc[2][2];
#pragma unroll
    for (int a = 0; a < 2; ++a)
#pragma unroll
        for (int bq2 = 0; bq2 < 2; ++bq2)
#pragma unroll
            for (int r = 0; r < 16; ++r) acc[a][bq2][r] = 0.f;

    loads(0);
    for (int kt = 0; kt < ND / 64; ++kt) {
        __syncthreads();
        writes();
        if (kt + 1 < ND / 64) loads(kt + 1);
        __syncthreads();
#pragma unroll
        for (int ks = 0; ks < 4; ++ks) {
            short8v afh[2], afl[2], bfh[2], bfl[2];
#pragma unroll
            for (int ms = 0; ms < 2; ++ms) {
                const int row = wm * 64 + ms * 32 + c;
                const int gb = row * 128 + (((2 * ks + hi) ^ (c & 7)) * 16);
                afh[ms] = *(const short8v*)(smem + AH + gb);
                afl[ms] = *(const short8v*)(smem + AL + gb);
            }
#pragma unroll
            for (int ns = 0; ns < 2; ++ns) {
                const int row = wn * 64 + ns * 32 + c;
                const int gb = row * 128 + (((2 * ks + hi) ^ (c & 7)) * 16);
                bfh[ns] = *(const short8v*)(smem + BH + gb);
                bfl[ns] = *(const short8v*)(smem + BL + gb);
            }
#pragma unroll
            for (int ms = 0; ms < 2; ++ms)
#pragma unroll
                for (int ns = 0; ns < 2; ++ns) {
                    acc[ms][ns] = MFMA32(afh[ms], bfh[ns], acc[ms][ns]);
                    acc[ms][ns] = MFMA32(afh[ms], bfl[ns], acc[ms][ns]);
                    acc[ms][ns] = MFMA32(afl[ms], bfh[ns], acc[ms][ns]);
                }
        }
    }

    const int b = m0 >> 11;
    const int s_base = (m0 & (NS - 1)) + wm * 64;
#pragma unroll
    for (int ns = 0; ns < 2; ++ns) {
        const int n = n0 + wn * 64 + ns * 32 + c;
        const int h = n >> 6, dk = n & (NDK - 1);
        const float bv4 = bias[n];
        const size_t bhBase = (size_t)(b * NH + h) * NS * NDK + dk;
#pragma unroll
        for (int ms = 0; ms < 2; ++ms)
#pragma unroll
            for (int r = 0; r < 16; ++r) {
                const int s = s_base + ms * 32 + (r & 3) + 8 * (r >> 2) + 4 * hi;
                const float v = acc[ms][ns][r] + bv4;
                const unsigned short h0 = f2bf(v);
                hp[bhBase + (size_t)s * NDK] = h0;
                if (lp) lp[bhBase + (size_t)s * NDK] = f2bf(v - bf2f(h0));
            }
    }
}

// ---------------------------------------------------------------------------
// vt_convert: V hi plane [bh][s][dv] -> [bh][dv][s].
// ---------------------------------------------------------------------------
__global__ __launch_bounds__(256) void vt_convert(
    const unsigned short* __restrict__ vh, unsigned short* __restrict__ vth)
{
    const int bh = blockIdx.y;
    const int s0 = blockIdx.x * 64;
    __shared__ unsigned short th[64][72];
    const int t = threadIdx.x;
    {
        const int sl = t & 63, ch = (t >> 6) * 16;
        const unsigned short* sh = vh + ((size_t)bh * NS + s0 + sl) * NDK + ch;
#pragma unroll
        for (int j = 0; j < 4; ++j)
            *(ushort4*)&th[sl][ch + 4 * j] = *(const ushort4*)(sh + 4 * j);
    }
    __syncthreads();
    {
        const int dv = t >> 2, sc = (t & 3) * 16;
        unsigned short* dh = vth + ((size_t)bh * NDK + dv) * NS + s0 + sc;
#pragma unroll
        for (int j = 0; j < 4; ++j) {
            ushort4 oh;
            oh.x = th[sc + 4 * j + 0][dv]; oh.y = th[sc + 4 * j + 1][dv];
            oh.z = th[sc + 4 * j + 2][dv]; oh.w = th[sc + 4 * j + 3][dv];
            *(ushort4*)(dh + 4 * j) = oh;
        }
    }
}

// ---------------------------------------------------------------------------
// attn: MFMA attention. Double-buffered K/V LDS (1 barrier/tile), P hi-only
// (1-term PV, denominator from rounded P -> common-mode cancellation),
// ctx out as single bf16 plane [bh][dv][s].
// ---------------------------------------------------------------------------
__global__ __launch_bounds__(256, 2) void attn(
    const unsigned short* __restrict__ qhp, const unsigned short* __restrict__ qlp,
    const unsigned short* __restrict__ khp, const unsigned short* __restrict__ klp,
    const unsigned short* __restrict__ vthp,
    const float* __restrict__ maskp,
    unsigned short* __restrict__ cth)
{
    constexpr int NT = NS / 64;
    constexpr int KH = 0, KL = 8192, VH = 16384, TILE = 24576;
    constexpr int P_OFF = 49152;           // Ph: 4 waves x 2560 B
    __shared__ __align__(16) unsigned char smem[59392];

    const int tid = threadIdx.x, lane = tid & 63, w = tid >> 6;
    const int bid = blockIdx.x;
    const int xcd = bid & 7, r0 = bid >> 3;
    const int qt = r0 & 15, bh = xcd + 8 * (r0 >> 4);
    const int b = bh >> 3;
    const int q0 = qt * 128;
    const int c = lane & 31, hi = lane >> 5;
    const int csw = (c & 7) * 16;

    unsigned* Ph = (unsigned*)(smem + P_OFF + w * 2560);

    const unsigned char* kh_base = (const unsigned char*)khp + (size_t)bh * NS * 128;
    const unsigned char* kl_base = (const unsigned char*)klp + (size_t)bh * NS * 128;
    const unsigned char* vh_base = (const unsigned char*)vthp + (size_t)bh * 64 * 4096;

    const int G1 = tid, G2 = tid + 256;
    const int r1 = G1 >> 3, g1 = G1 & 7, r2 = G2 >> 3, g2 = G2 & 7;
    const int d1 = r1 * 128 + ((g1 ^ (r1 & 7)) * 16);
    const int d2 = r2 * 128 + ((g2 ^ (r2 & 7)) * 16);

    uint4v skh1, skl1, svh1, skh2, skl2, svh2;
    auto loads = [&](int kt) {
        const size_t ko = (size_t)kt * 8192;
        const size_t vo = (size_t)kt * 128;
        skh1 = *(const uint4v*)(kh_base + ko + (size_t)G1 * 16);
        skh2 = *(const uint4v*)(kh_base + ko + (size_t)G2 * 16);
        skl1 = *(const uint4v*)(kl_base + ko + (size_t)G1 * 16);
        skl2 = *(const uint4v*)(kl_base + ko + (size_t)G2 * 16);
        svh1 = *(const uint4v*)(vh_base + vo + (size_t)r1 * 4096 + g1 * 16);
        svh2 = *(const uint4v*)(vh_base + vo + (size_t)r2 * 4096 + g2 * 16);
    };
    auto writes = [&](unsigned char* buf) {
        *(uint4v*)(buf + KH + d1) = skh1;
        *(uint4v*)(buf + KH + d2) = skh2;
        *(uint4v*)(buf + KL + d1) = skl1;
        *(uint4v*)(buf + KL + d2) = skl2;
        *(uint4v*)(buf + VH + d1) = svh1;
        *(uint4v*)(buf + VH + d2) = svh2;
    };

    short8v qfh[4], qfl[4];
    {
        const unsigned short* qr  = qhp + ((size_t)bh * NS + q0 + 32 * w + c) * NDK + 8 * hi;
        const unsigned short* qrl = qlp + ((size_t)bh * NS + q0 + 32 * w + c) * NDK + 8 * hi;
#pragma unroll
        for (int km = 0; km < 4; ++km) {
            qfh[km] = *(const short8v*)(qr + km * 16);
            qfl[km] = *(const short8v*)(qrl + km * 16);
        }
    }

    f32x16v acc[2];
#pragma unroll
    for (int d = 0; d < 2; ++d)
#pragma unroll
        for (int r = 0; r < 16; ++r) acc[d][r] = 0.f;
    float dsum = 0.f;

    auto compute = [&](const unsigned char* buf, int kt) {
#pragma unroll
        for (int kb = 0; kb < 2; ++kb) {
            short8v kfh[4], kfl[4];
            const int rowb = (32 * kb + c) * 128;
#pragma unroll
            for (int km = 0; km < 4; ++km) {
                const int gb = ((2 * km + hi) * 16) ^ csw;
                kfh[km] = *(const short8v*)(buf + KH + rowb + gb);
                kfl[km] = *(const short8v*)(buf + KL + rowb + gb);
            }
            f32x16v sacc;
#pragma unroll
            for (int r = 0; r < 16; ++r) sacc[r] = 0.f;
#pragma unroll
            for (int km = 0; km < 4; ++km) {
                sacc = MFMA32(kfh[km], qfh[km], sacc);
                sacc = MFMA32(kfh[km], qfl[km], sacc);
                sacc = MFMA32(kfl[km], qfh[km], sacc);
            }
            float pm[16];
#pragma unroll
            for (int rr2 = 0; rr2 < 4; ++rr2) {
                float4 mv = *(const float4*)&maskp[(size_t)b * NS + kt * 64 + 32 * kb + 8 * rr2 + 4 * hi];
                pm[4 * rr2 + 0] = mv.x; pm[4 * rr2 + 1] = mv.y;
                pm[4 * rr2 + 2] = mv.z; pm[4 * rr2 + 3] = mv.w;
            }
            // p = exp2(s * 0.125*log2e) * mask, rounded to bf16; denom from
            // the ROUNDED p (numerator/denominator rounding cancels).
            unsigned short hh[16];
#pragma unroll
            for (int r = 0; r < 16; ++r) {
                float pv = exp2f(sacc[r] * 0.18033688011112042f) * pm[r];
                hh[r] = f2bf(pv);
                dsum += bf2f(hh[r]);
            }
            unsigned wah[4], wbh[4];
#pragma unroll
            for (int rr2 = 0; rr2 < 4; ++rr2) {
                wah[rr2] = (unsigned)hh[4 * rr2 + 0] | ((unsigned)hh[4 * rr2 + 1] << 16);
                wbh[rr2] = (unsigned)hh[4 * rr2 + 2] | ((unsigned)hh[4 * rr2 + 3] << 16);
            }
#pragma unroll
            for (int rr2 = 0; rr2 < 4; ++rr2) {
                uint2 th2; th2.x = wah[rr2]; th2.y = wbh[rr2];
                *(uint2*)&Ph[c * 20 + 4 * rr2 + 2 * hi] = th2;
            }
            asm volatile("s_waitcnt lgkmcnt(0)" ::: "memory");
            __builtin_amdgcn_sched_barrier(0);
#pragma unroll
            for (int pc2 = 0; pc2 < 2; ++pc2) {
                const int pc = 2 * kb + pc2;
                uint4v th4 = *(const uint4v*)&Ph[c * 20 + 8 * pc2 + 4 * hi];
                short8v pfh = __builtin_bit_cast(short8v, th4);
                const int vgb = ((2 * pc + hi) * 16) ^ csw;
#pragma unroll
                for (int d = 0; d < 2; ++d) {
                    const int vrow = (32 * d + c) * 128;
                    short8v vfh = *(const short8v*)(buf + VH + vrow + vgb);
                    acc[d] = MFMA32(vfh, pfh, acc[d]);
                }
            }
        }
    };

    unsigned char* buf0 = smem;
    unsigned char* buf1 = smem + TILE;

    // prologue: tile0 -> buf0, tile1 -> regs
    loads(0);
    writes(buf0);
    loads(1);
    __syncthreads();

    auto step = [&](int kt, unsigned char* rbuf, unsigned char* wbuf) {
        if (kt + 1 < NT) writes(wbuf);     // stash tile kt+1 (regs -> LDS)
        if (kt + 2 < NT) loads(kt + 2);    // refill regs (anti-dep after writes)
        compute(rbuf, kt);
        __syncthreads();                   // wbuf visible; rbuf reads done
    };
    for (int kt = 0; kt < NT; kt += 2) {
        step(kt, buf0, buf1);
        step(kt + 1, buf1, buf0);
    }

    dsum += __shfl_xor(dsum, 32);
    const float inv = 1.0f / (dsum + 1e-8f);
    unsigned short* ohr = cth + (size_t)bh * 64 * NS + q0 + 32 * w + c;
#pragma unroll
    for (int d = 0; d < 2; ++d)
#pragma unroll
        for (int r = 0; r < 16; ++r) {
            const int dv = 32 * d + (r & 3) + 8 * (r >> 2) + 4 * hi;
            ohr[(size_t)dv * NS] = f2bf(acc[d][r] * inv);
        }
}

// ---------------------------------------------------------------------------
// ctx_split: bf16 plane [bh][dv][s] -> natural [b*s][h*64+dv].
// ---------------------------------------------------------------------------
__global__ __launch_bounds__(256) void ctx_split(
    const unsigned short* __restrict__ cth, unsigned short* __restrict__ cnh)
{
    const int bh = blockIdx.y;
    const int b = bh >> 3, h = bh & 7;
    const int s0 = blockIdx.x * 64;
    __shared__ unsigned short th[64][72];
    const int t = threadIdx.x;
    {
        const int rd = t >> 2, sc = (t & 3) * 16;
        const unsigned short* sh = cth + ((size_t)bh * NDK + rd) * NS + s0 + sc;
#pragma unroll
        for (int j = 0; j < 4; ++j)
            *(ushort4*)&th[rd][sc + 4 * j] = *(const ushort4*)(sh + 4 * j);
    }
    __syncthreads();
    {
        const int sl = t >> 2, kc = (t & 3) * 16;
        const size_t m = (size_t)b * NS + s0 + sl;
        unsigned short* dh = cnh + m * NHD + h * NDK + kc;
#pragma unroll
        for (int j = 0; j < 4; ++j) {
            ushort4 hh;
#pragma unroll
            for (int e = 0; e < 4; ++e)
                ((unsigned short*)&hh)[e] = th[kc + 4 * j + e][sl];
            *(ushort4*)(dh + 4 * j) = hh;
        }
    }
}

// ---------------------------------------------------------------------------
// proj_out_mfma: out = ctx(bf16) @ Wo + bo — 2-term split MFMA (A hi-only).
// ---------------------------------------------------------------------------
__global__ __launch_bounds__(256, 2) void proj_out_mfma(
    const unsigned short* __restrict__ cnh,
    const unsigned short* __restrict__ wth, const unsigned short* __restrict__ wtl,
    const float* __restrict__ bo, float* __restrict__ out)
{
    constexpr int AH = 0, BH = 16384, BL = 32768;
    __shared__ __align__(16) unsigned char smem[49152];

    const int tid = threadIdx.x, lane = tid & 63, w = tid >> 6;
    const int wm = w >> 1, wn = w & 1;
    const int c = lane & 31, hi = lane >> 5;
    const int m0 = blockIdx.y * 128, n0 = blockIdx.x * 128;

    const unsigned char* ah_base = (const unsigned char*)cnh;
    const unsigned char* bth = (const unsigned char*)wth;
    const unsigned char* btl = (const unsigned char*)wtl;

    int rr[4], gg[4], dd[4];
#pragma unroll
    for (int i = 0; i < 4; ++i) {
        int G = tid + 256 * i;
        rr[i] = G >> 3; gg[i] = G & 7;
        dd[i] = rr[i] * 128 + ((gg[i] ^ (rr[i] & 7)) * 16);
    }

    uint4v sah[4], sbh[4], sbl[4];
    auto loads = [&](int kt) {
        const int kb = kt * 128;
#pragma unroll
        for (int i = 0; i < 4; ++i) {
            const size_t arow = (size_t)(m0 + rr[i]) * 1024 + kb + gg[i] * 16;
            const size_t brow = (size_t)(n0 + rr[i]) * 1024 + kb + gg[i] * 16;
            sah[i] = *(const uint4v*)(ah_base + arow);
            sbh[i] = *(const uint4v*)(bth + brow);
            sbl[i] = *(const uint4v*)(btl + brow);
        }
    };
    auto writes = [&]() {
#pragma unroll
        for (int i = 0; i < 4; ++i) {
            *(uint4v*)(smem + AH + dd[i]) = sah[i];
            *(uint4v*)(smem + BH + dd[i]) = sbh[i];
            *(uint4v*)(smem + BL + dd[i]) = sbl[i];
        }
    };

    f32x16v acc[2][2];
#pragma unroll
    for (int a = 0; a < 2; ++a)
#pragma unroll
        for (int bq2 = 0; bq2 < 2; ++bq2)
#pragma unroll
            for (int r = 0; r < 16; ++r) acc[a][bq2][r] = 0.f;

    loads(0);
    for (int kt = 0; kt < NHD / 64; ++kt) {
        __syncthreads();
        writes();
        if (kt + 1 < NHD / 64) loads(kt + 1);
        __syncthreads();
#pragma unroll
        for (int ks = 0; ks < 4; ++ks) {
            short8v afh[2], bfh[2], bfl[2];
#pragma unroll
            for (int ms = 0; ms < 2; ++ms) {
                const int row = wm * 64 + ms * 32 + c;
                const int gb = row * 128 + (((2 * ks + hi) ^ (c & 7)) * 16);
                afh[ms] = *(const short8v*)(smem + AH + gb);
            }
#pragma unroll
            for (int ns = 0; ns < 2; ++ns) {
                const int row = wn * 64 + ns * 32 + c;
                const int gb = row * 128 + (((2 * ks + hi) ^ (c & 7)) * 16);
                bfh[ns] = *(const short8v*)(smem + BH + gb);
                bfl[ns] = *(const short8v*)(smem + BL + gb);
            }
#pragma unroll
            for (int ms = 0; ms < 2; ++ms)
#pragma unroll
                for (int ns = 0; ns < 2; ++ns) {
                    acc[ms][ns] = MFMA32(afh[ms], bfh[ns], acc[ms][ns]);
                    acc[ms][ns] = MFMA32(afh[ms], bfl[ns], acc[ms][ns]);
                }
        }
    }

#pragma unroll
    for (int ns = 0; ns < 2; ++ns) {
        const int n = n0 + wn * 64 + ns * 32 + c;
        const float bv4 = bo[n];
#pragma unroll
        for (int ms = 0; ms < 2; ++ms)
#pragma unroll
            for (int r = 0; r < 16; ++r) {
                const int m = m0 + wm * 64 + ms * 32 + (r & 3) + 8 * (r >> 2) + 4 * hi;
                out[(size_t)m * ND + n] = acc[ms][ns][r] + bv4;
            }
    }
}

// ---------------------------------------------------------------------------
extern "C" void kernel_launch(void* const* d_in, const int* in_sizes, int n_in,
                              void* d_out, int out_size, void* d_ws, size_t ws_size,
                              hipStream_t stream) {
    const float* Q    = (const float*)d_in[0];
    const float* mask = (const float*)d_in[1];
    const float* Wq   = (const float*)d_in[2];
    const float* bq   = (const float*)d_in[3];
    const float* Wk   = (const float*)d_in[4];
    const float* bk   = (const float*)d_in[5];
    const float* Wv   = (const float*)d_in[6];
    const float* bv   = (const float*)d_in[7];
    const float* Wo   = (const float*)d_in[8];
    const float* bo   = (const float*)d_in[9];

    unsigned char* W = (unsigned char*)d_ws;
    constexpr size_t MB = 1048576;
    // live-range-audited layout (no read/write overlap within any kernel):
    unsigned short* xh   = (unsigned short*)(W + 0);         // split_x .. proj_qkv
    unsigned short* xl   = (unsigned short*)(W + 8 * MB);    // split_x .. proj_qkv
    unsigned short* wtH  = (unsigned short*)(W + 16 * MB);   // split_wT .. proj_out
    unsigned short* wtL  = (unsigned short*)(W + 18 * MB);
    unsigned short* qh   = (unsigned short*)(W + 20 * MB);   // proj_qkv .. attn
    unsigned short* ql   = (unsigned short*)(W + 28 * MB);
    unsigned short* kh   = (unsigned short*)(W + 36 * MB);
    unsigned short* kl   = (unsigned short*)(W + 44 * MB);
    unsigned short* vh   = (unsigned short*)(W + 52 * MB);   // proj_qkv .. vt_convert
    unsigned short* vth  = (unsigned short*)(W + 0);         // vt_convert .. attn (over xh)
    unsigned short* cth  = (unsigned short*)(W + 8 * MB);    // attn .. ctx_split (over xl)
    unsigned short* cnh  = (unsigned short*)(W + 20 * MB);   // ctx_split .. proj_out (over qh)

    split_x<<<NM * ND / (256 * 16), 256, 0, stream>>>(Q, xh, xl);
    split_wT<<<dim3(8, 8, 4), 256, 0, stream>>>(Wq, Wk, Wv, Wo, wtH, wtL);

    proj_qkv_mfma<<<dim3(NHD / 128, NM / 128, 3), 256, 0, stream>>>(
        xh, xl, wtH, wtL, bq, bk, bv, qh, ql, kh, kl, vh);

    vt_convert<<<dim3(NS / 64, NB * NH), 256, 0, stream>>>(vh, vth);

    attn<<<512, 256, 0, stream>>>(qh, ql, kh, kl, vth, mask, cth);

    ctx_split<<<dim3(NS / 64, NB * NH), 256, 0, stream>>>(cth, cnh);

    proj_out_mfma<<<dim3(ND / 128, NM / 128), 256, 0, stream>>>(
        cnh, wtH + (size_t)3 * ND * ND, wtL + (size_t)3 * ND * ND,
        bo, (float*)d_out);
}

// Round 8
// 238.944 us; speedup vs baseline: 3.4703x; 1.1001x over previous
//
#include <hip/hip_runtime.h>
#include <math.h>

constexpr int NB = 4, NS = 2048, ND = 512, NH = 8, NDK = 64;
constexpr int NM = NB * NS, NHD = NH * NDK;

typedef short short8v __attribute__((ext_vector_type(8)));
typedef float f32x16v __attribute__((ext_vector_type(16)));
typedef unsigned int uint4v __attribute__((ext_vector_type(4)));

__device__ __forceinline__ unsigned short f2bf(float f) {
    unsigned u = __float_as_uint(f);
    return (unsigned short)((u + 0x7fffu + ((u >> 16) & 1u)) >> 16);
}
__device__ __forceinline__ float bf2f(unsigned short h) {
    return __uint_as_float(((unsigned)h) << 16);
}

#define MFMA32(a, b, c) __builtin_amdgcn_mfma_f32_32x32x16_bf16(a, b, c, 0, 0, 0)

// ---------------------------------------------------------------------------
// split_x: X fp32 [8192*512] -> Xh, Xl bf16 planes.
// ---------------------------------------------------------------------------
__global__ __launch_bounds__(256) void split_x(
    const float* __restrict__ X, unsigned short* __restrict__ xh,
    unsigned short* __restrict__ xl)
{
    const size_t base = ((size_t)blockIdx.x * 256 + threadIdx.x) * 16;
#pragma unroll
    for (int j = 0; j < 4; ++j) {
        float4 v = *(const float4*)&X[base + 4 * j];
        ushort4 h, l;
        h.x = f2bf(v.x); h.y = f2bf(v.y); h.z = f2bf(v.z); h.w = f2bf(v.w);
        l.x = f2bf(v.x - bf2f(h.x)); l.y = f2bf(v.y - bf2f(h.y));
        l.z = f2bf(v.z - bf2f(h.z)); l.w = f2bf(v.w - bf2f(h.w));
        *(ushort4*)&xh[base + 4 * j] = h;
        *(ushort4*)&xl[base + 4 * j] = l;
    }
}

// ---------------------------------------------------------------------------
// split_wT: W fp32 [512][512] -> WTh, WTl bf16 [n][k] (transposed).
// ---------------------------------------------------------------------------
__global__ __launch_bounds__(256) void split_wT(
    const float* __restrict__ W0, const float* __restrict__ W1,
    const float* __restrict__ W2, const float* __restrict__ W3,
    unsigned short* __restrict__ wth, unsigned short* __restrict__ wtl)
{
    const int z = blockIdx.z;
    const float* W = (z == 0) ? W0 : (z == 1) ? W1 : (z == 2) ? W2 : W3;
    unsigned short* th = wth + (size_t)z * ND * ND;
    unsigned short* tl = wtl + (size_t)z * ND * ND;

    __shared__ float T[64][68];
    const int t = threadIdx.x;
    const int k0 = blockIdx.y * 64, n0 = blockIdx.x * 64;
    {
        const int r = t >> 2, c4 = (t & 3) * 16;
#pragma unroll
        for (int j = 0; j < 4; ++j)
            *(float4*)&T[r][c4 + 4 * j] = *(const float4*)&W[(size_t)(k0 + r) * ND + n0 + c4 + 4 * j];
    }
    __syncthreads();
    {
        const int r = t >> 2, c4 = (t & 3) * 16;
        unsigned short* dh = th + (size_t)(n0 + r) * ND + k0 + c4;
        unsigned short* dl = tl + (size_t)(n0 + r) * ND + k0 + c4;
#pragma unroll
        for (int j = 0; j < 4; ++j) {
            ushort4 h, l;
#pragma unroll
            for (int e = 0; e < 4; ++e) {
                float v = T[c4 + 4 * j + e][r];
                unsigned short hh = f2bf(v);
                ((unsigned short*)&h)[e] = hh;
                ((unsigned short*)&l)[e] = f2bf(v - bf2f(hh));
            }
            *(ushort4*)(dh + 4 * j) = h;
            *(ushort4*)(dl + 4 * j) = l;
        }
    }
}

// ---------------------------------------------------------------------------
// proj_qkv_mfma: C = X @ W + b via 3-term split-bf16 MFMA. 128x128 tile,
// BK=64, 4 waves (2x2). z: 0=q (pre-scaled by 0.125*log2e), 1=k, 2=v (hi only).
// ---------------------------------------------------------------------------
__global__ __launch_bounds__(256, 2) void proj_qkv_mfma(
    const unsigned short* __restrict__ xh, const unsigned short* __restrict__ xl,
    const unsigned short* __restrict__ wth, const unsigned short* __restrict__ wtl,
    const float* __restrict__ bq, const float* __restrict__ bk,
    const float* __restrict__ bv,
    unsigned short* __restrict__ qh, unsigned short* __restrict__ ql,
    unsigned short* __restrict__ kh, unsigned short* __restrict__ kl,
    unsigned short* __restrict__ vh)
{
    constexpr int AH = 0, AL = 16384, BH = 32768, BL = 49152;
    __shared__ __align__(16) unsigned char smem[65536];

    const int z = blockIdx.z;
    const float* bias = (z == 0) ? bq : (z == 1) ? bk : bv;
    unsigned short* hp = (z == 0) ? qh : (z == 1) ? kh : vh;
    unsigned short* lp = (z == 0) ? ql : (z == 1) ? kl : (unsigned short*)0;
    const float sc = (z == 0) ? 0.18033688011112042f : 1.0f;  // fold softmax scale into Q
    const unsigned char* bth = (const unsigned char*)(wth + (size_t)z * ND * ND);
    const unsigned char* btl = (const unsigned char*)(wtl + (size_t)z * ND * ND);

    const int tid = threadIdx.x, lane = tid & 63, w = tid >> 6;
    const int wm = w >> 1, wn = w & 1;
    const int c = lane & 31, hi = lane >> 5;
    const int m0 = blockIdx.y * 128, n0 = blockIdx.x * 128;

    const unsigned char* ah_base = (const unsigned char*)xh;
    const unsigned char* al_base = (const unsigned char*)xl;

    int rr[4], gg[4], dd[4];
#pragma unroll
    for (int i = 0; i < 4; ++i) {
        int G = tid + 256 * i;
        rr[i] = G >> 3; gg[i] = G & 7;
        dd[i] = rr[i] * 128 + ((gg[i] ^ (rr[i] & 7)) * 16);
    }

    uint4v sah[4], sal[4], sbh[4], sbl[4];
    auto loads = [&](int kt) {
        const int kb = kt * 128;
#pragma unroll
        for (int i = 0; i < 4; ++i) {
            const size_t arow = (size_t)(m0 + rr[i]) * 1024 + kb + gg[i] * 16;
            const size_t brow = (size_t)(n0 + rr[i]) * 1024 + kb + gg[i] * 16;
            sah[i] = *(const uint4v*)(ah_base + arow);
            sal[i] = *(const uint4v*)(al_base + arow);
            sbh[i] = *(const uint4v*)(bth + brow);
            sbl[i] = *(const uint4v*)(btl + brow);
        }
    };
    auto writes = [&]() {
#pragma unroll
        for (int i = 0; i < 4; ++i) {
            *(uint4v*)(smem + AH + dd[i]) = sah[i];
            *(uint4v*)(smem + AL + dd[i]) = sal[i];
            *(uint4v*)(smem + BH + dd[i]) = sbh[i];
            *(uint4v*)(smem + BL + dd[i]) = sbl[i];
        }
    };

    f32x16v acc[2][2];
#pragma unroll
    for (int a = 0; a < 2; ++a)
#pragma unroll
        for (int bq2 = 0; bq2 < 2; ++bq2)
#pragma unroll
            for (int r = 0; r < 16; ++r) acc[a][bq2][r] = 0.f;

    loads(0);
    for (int kt = 0; kt < ND / 64; ++kt) {
        __syncthreads();
        writes();
        if (kt + 1 < ND / 64) loads(kt + 1);
        __syncthreads();
#pragma unroll
        for (int ks = 0; ks < 4; ++ks) {
            short8v afh[2], afl[2], bfh[2], bfl[2];
#pragma unroll
            for (int ms = 0; ms < 2; ++ms) {
                const int row = wm * 64 + ms * 32 + c;
                const int gb = row * 128 + (((2 * ks + hi) ^ (c & 7)) * 16);
                afh[ms] = *(const short8v*)(smem + AH + gb);
                afl[ms] = *(const short8v*)(smem + AL + gb);
            }
#pragma unroll
            for (int ns = 0; ns < 2; ++ns) {
                const int row = wn * 64 + ns * 32 + c;
                const int gb = row * 128 + (((2 * ks + hi) ^ (c & 7)) * 16);
                bfh[ns] = *(const short8v*)(smem + BH + gb);
                bfl[ns] = *(const short8v*)(smem + BL + gb);
            }
#pragma unroll
            for (int ms = 0; ms < 2; ++ms)
#pragma unroll
                for (int ns = 0; ns < 2; ++ns) {
                    acc[ms][ns] = MFMA32(afh[ms], bfh[ns], acc[ms][ns]);
                    acc[ms][ns] = MFMA32(afh[ms], bfl[ns], acc[ms][ns]);
                    acc[ms][ns] = MFMA32(afl[ms], bfh[ns], acc[ms][ns]);
                }
        }
    }

    const int b = m0 >> 11;
    const int s_base = (m0 & (NS - 1)) + wm * 64;
#pragma unroll
    for (int ns = 0; ns < 2; ++ns) {
        const int n = n0 + wn * 64 + ns * 32 + c;
        const int h = n >> 6, dk = n & (NDK - 1);
        const float bv4 = bias[n];
        const size_t bhBase = (size_t)(b * NH + h) * NS * NDK + dk;
#pragma unroll
        for (int ms = 0; ms < 2; ++ms)
#pragma unroll
            for (int r = 0; r < 16; ++r) {
                const int s = s_base + ms * 32 + (r & 3) + 8 * (r >> 2) + 4 * hi;
                const float v = (acc[ms][ns][r] + bv4) * sc;
                const unsigned short h0 = f2bf(v);
                hp[bhBase + (size_t)s * NDK] = h0;
                if (lp) lp[bhBase + (size_t)s * NDK] = f2bf(v - bf2f(h0));
            }
    }
}

// ---------------------------------------------------------------------------
// vt_convert: V hi plane [bh][s][dv] -> [bh][dv][s].
// ---------------------------------------------------------------------------
__global__ __launch_bounds__(256) void vt_convert(
    const unsigned short* __restrict__ vh, unsigned short* __restrict__ vth)
{
    const int bh = blockIdx.y;
    const int s0 = blockIdx.x * 64;
    __shared__ unsigned short th[64][72];
    const int t = threadIdx.x;
    {
        const int sl = t & 63, ch = (t >> 6) * 16;
        const unsigned short* sh = vh + ((size_t)bh * NS + s0 + sl) * NDK + ch;
#pragma unroll
        for (int j = 0; j < 4; ++j)
            *(ushort4*)&th[sl][ch + 4 * j] = *(const ushort4*)(sh + 4 * j);
    }
    __syncthreads();
    {
        const int dv = t >> 2, sc = (t & 3) * 16;
        unsigned short* dh = vth + ((size_t)bh * NDK + dv) * NS + s0 + sc;
#pragma unroll
        for (int j = 0; j < 4; ++j) {
            ushort4 oh;
            oh.x = th[sc + 4 * j + 0][dv]; oh.y = th[sc + 4 * j + 1][dv];
            oh.z = th[sc + 4 * j + 2][dv]; oh.w = th[sc + 4 * j + 3][dv];
            *(ushort4*)(dh + 4 * j) = oh;
        }
    }
}

// ---------------------------------------------------------------------------
// attn: MFMA attention. Double-buffered K/V LDS (1 barrier/tile).
// Q pre-scaled so p = v_exp_f32(s) * mask. P packed via v_cvt_pk_bf16_f32;
// denominator from ROUNDED P (common-mode). 2 QK accumulators; 4 dsum partials.
// ---------------------------------------------------------------------------
__global__ __launch_bounds__(256, 2) void attn(
    const unsigned short* __restrict__ qhp, const unsigned short* __restrict__ qlp,
    const unsigned short* __restrict__ khp, const unsigned short* __restrict__ klp,
    const unsigned short* __restrict__ vthp,
    const float* __restrict__ maskp,
    unsigned short* __restrict__ cth)
{
    constexpr int NT = NS / 64;
    constexpr int KH = 0, KL = 8192, VH = 16384, TILE = 24576;
    constexpr int P_OFF = 49152;           // Ph: 4 waves x 2560 B
    __shared__ __align__(16) unsigned char smem[59392];

    const int tid = threadIdx.x, lane = tid & 63, w = tid >> 6;
    const int bid = blockIdx.x;
    const int xcd = bid & 7, r0 = bid >> 3;
    const int qt = r0 & 15, bh = xcd + 8 * (r0 >> 4);
    const int b = bh >> 3;
    const int q0 = qt * 128;
    const int c = lane & 31, hi = lane >> 5;
    const int csw = (c & 7) * 16;

    unsigned* Ph = (unsigned*)(smem + P_OFF + w * 2560);

    const unsigned char* kh_base = (const unsigned char*)khp + (size_t)bh * NS * 128;
    const unsigned char* kl_base = (const unsigned char*)klp + (size_t)bh * NS * 128;
    const unsigned char* vh_base = (const unsigned char*)vthp + (size_t)bh * 64 * 4096;

    const int G1 = tid, G2 = tid + 256;
    const int r1 = G1 >> 3, g1 = G1 & 7, r2 = G2 >> 3, g2 = G2 & 7;
    const int d1 = r1 * 128 + ((g1 ^ (r1 & 7)) * 16);
    const int d2 = r2 * 128 + ((g2 ^ (r2 & 7)) * 16);

    uint4v skh1, skl1, svh1, skh2, skl2, svh2;
    auto loads = [&](int kt) {
        const size_t ko = (size_t)kt * 8192;
        const size_t vo = (size_t)kt * 128;
        skh1 = *(const uint4v*)(kh_base + ko + (size_t)G1 * 16);
        skh2 = *(const uint4v*)(kh_base + ko + (size_t)G2 * 16);
        skl1 = *(const uint4v*)(kl_base + ko + (size_t)G1 * 16);
        skl2 = *(const uint4v*)(kl_base + ko + (size_t)G2 * 16);
        svh1 = *(const uint4v*)(vh_base + vo + (size_t)r1 * 4096 + g1 * 16);
        svh2 = *(const uint4v*)(vh_base + vo + (size_t)r2 * 4096 + g2 * 16);
    };
    auto writes = [&](unsigned char* buf) {
        *(uint4v*)(buf + KH + d1) = skh1;
        *(uint4v*)(buf + KH + d2) = skh2;
        *(uint4v*)(buf + KL + d1) = skl1;
        *(uint4v*)(buf + KL + d2) = skl2;
        *(uint4v*)(buf + VH + d1) = svh1;
        *(uint4v*)(buf + VH + d2) = svh2;
    };

    short8v qfh[4], qfl[4];
    {
        const unsigned short* qr  = qhp + ((size_t)bh * NS + q0 + 32 * w + c) * NDK + 8 * hi;
        const unsigned short* qrl = qlp + ((size_t)bh * NS + q0 + 32 * w + c) * NDK + 8 * hi;
#pragma unroll
        for (int km = 0; km < 4; ++km) {
            qfh[km] = *(const short8v*)(qr + km * 16);
            qfl[km] = *(const short8v*)(qrl + km * 16);
        }
    }

    f32x16v acc[2];
#pragma unroll
    for (int d = 0; d < 2; ++d)
#pragma unroll
        for (int r = 0; r < 16; ++r) acc[d][r] = 0.f;
    float dsp0 = 0.f, dsp1 = 0.f, dsp2 = 0.f, dsp3 = 0.f;

    auto compute = [&](const unsigned char* buf, int kt) {
#pragma unroll
        for (int kb = 0; kb < 2; ++kb) {
            short8v kfh[4], kfl[4];
            const int rowb = (32 * kb + c) * 128;
#pragma unroll
            for (int km = 0; km < 4; ++km) {
                const int gb = ((2 * km + hi) * 16) ^ csw;
                kfh[km] = *(const short8v*)(buf + KH + rowb + gb);
                kfl[km] = *(const short8v*)(buf + KL + rowb + gb);
            }
            // two independent accumulation chains (8 + 4) to hide MFMA latency
            f32x16v s0, s1;
#pragma unroll
            for (int r = 0; r < 16; ++r) { s0[r] = 0.f; s1[r] = 0.f; }
#pragma unroll
            for (int km = 0; km < 4; ++km) {
                s0 = MFMA32(kfh[km], qfh[km], s0);
                s1 = MFMA32(kfh[km], qfl[km], s1);
            }
#pragma unroll
            for (int km = 0; km < 4; ++km)
                s0 = MFMA32(kfl[km], qfh[km], s0);

            float pm[16];
#pragma unroll
            for (int rr2 = 0; rr2 < 4; ++rr2) {
                float4 mv = *(const float4*)&maskp[(size_t)b * NS + kt * 64 + 32 * kb + 8 * rr2 + 4 * hi];
                pm[4 * rr2 + 0] = mv.x; pm[4 * rr2 + 1] = mv.y;
                pm[4 * rr2 + 2] = mv.z; pm[4 * rr2 + 3] = mv.w;
            }
            // p = exp2(s) * mask (Q pre-scaled); pack pairs; denom from rounded P
            unsigned wph[8];
#pragma unroll
            for (int p2 = 0; p2 < 8; ++p2) {
                float x0 = s0[2 * p2] + s1[2 * p2];
                float x1 = s0[2 * p2 + 1] + s1[2 * p2 + 1];
                float e0, e1;
                asm("v_exp_f32 %0, %1" : "=v"(e0) : "v"(x0));
                asm("v_exp_f32 %0, %1" : "=v"(e1) : "v"(x1));
                e0 *= pm[2 * p2];
                e1 *= pm[2 * p2 + 1];
                unsigned wv;
                asm("v_cvt_pk_bf16_f32 %0, %1, %2" : "=v"(wv) : "v"(e0), "v"(e1));
                wph[p2] = wv;
                float dlo = __uint_as_float(wv << 16);
                float dhi = __uint_as_float(wv & 0xffff0000u);
                if ((p2 & 3) == 0) dsp0 += dlo + dhi;
                else if ((p2 & 3) == 1) dsp1 += dlo + dhi;
                else if ((p2 & 3) == 2) dsp2 += dlo + dhi;
                else dsp3 += dlo + dhi;
            }
#pragma unroll
            for (int rr2 = 0; rr2 < 4; ++rr2) {
                uint2 th2; th2.x = wph[2 * rr2]; th2.y = wph[2 * rr2 + 1];
                *(uint2*)&Ph[c * 20 + 4 * rr2 + 2 * hi] = th2;
            }
            asm volatile("s_waitcnt lgkmcnt(0)" ::: "memory");
            __builtin_amdgcn_sched_barrier(0);
#pragma unroll
            for (int pc2 = 0; pc2 < 2; ++pc2) {
                const int pc = 2 * kb + pc2;
                uint4v th4 = *(const uint4v*)&Ph[c * 20 + 8 * pc2 + 4 * hi];
                short8v pfh = __builtin_bit_cast(short8v, th4);
                const int vgb = ((2 * pc + hi) * 16) ^ csw;
#pragma unroll
                for (int d = 0; d < 2; ++d) {
                    const int vrow = (32 * d + c) * 128;
                    short8v vfh = *(const short8v*)(buf + VH + vrow + vgb);
                    acc[d] = MFMA32(vfh, pfh, acc[d]);
                }
            }
        }
    };

    unsigned char* buf0 = smem;
    unsigned char* buf1 = smem + TILE;

    loads(0);
    writes(buf0);
    loads(1);
    __syncthreads();

    auto step = [&](int kt, unsigned char* rbuf, unsigned char* wbuf) {
        if (kt + 1 < NT) writes(wbuf);
        if (kt + 2 < NT) loads(kt + 2);
        compute(rbuf, kt);
        __syncthreads();
    };
    for (int kt = 0; kt < NT; kt += 2) {
        step(kt, buf0, buf1);
        step(kt + 1, buf1, buf0);
    }

    float dsum = (dsp0 + dsp1) + (dsp2 + dsp3);
    dsum += __shfl_xor(dsum, 32);
    const float inv = 1.0f / (dsum + 1e-8f);
    unsigned short* ohr = cth + (size_t)bh * 64 * NS + q0 + 32 * w + c;
#pragma unroll
    for (int d = 0; d < 2; ++d)
#pragma unroll
        for (int r = 0; r < 16; ++r) {
            const int dv = 32 * d + (r & 3) + 8 * (r >> 2) + 4 * hi;
            ohr[(size_t)dv * NS] = f2bf(acc[d][r] * inv);
        }
}

// ---------------------------------------------------------------------------
// ctx_split: bf16 plane [bh][dv][s] -> natural [b*s][h*64+dv].
// ---------------------------------------------------------------------------
__global__ __launch_bounds__(256) void ctx_split(
    const unsigned short* __restrict__ cth, unsigned short* __restrict__ cnh)
{
    const int bh = blockIdx.y;
    const int b = bh >> 3, h = bh & 7;
    const int s0 = blockIdx.x * 64;
    __shared__ unsigned short th[64][72];
    const int t = threadIdx.x;
    {
        const int rd = t >> 2, sc = (t & 3) * 16;
        const unsigned short* sh = cth + ((size_t)bh * NDK + rd) * NS + s0 + sc;
#pragma unroll
        for (int j = 0; j < 4; ++j)
            *(ushort4*)&th[rd][sc + 4 * j] = *(const ushort4*)(sh + 4 * j);
    }
    __syncthreads();
    {
        const int sl = t >> 2, kc = (t & 3) * 16;
        const size_t m = (size_t)b * NS + s0 + sl;
        unsigned short* dh = cnh + m * NHD + h * NDK + kc;
#pragma unroll
        for (int j = 0; j < 4; ++j) {
            ushort4 hh;
#pragma unroll
            for (int e = 0; e < 4; ++e)
                ((unsigned short*)&hh)[e] = th[kc + 4 * j + e][sl];
            *(ushort4*)(dh + 4 * j) = hh;
        }
    }
}

// ---------------------------------------------------------------------------
// proj_out_mfma: out = ctx(bf16) @ Wo + bo — 2-term split MFMA (A hi-only).
// ---------------------------------------------------------------------------
__global__ __launch_bounds__(256, 2) void proj_out_mfma(
    const unsigned short* __restrict__ cnh,
    const unsigned short* __restrict__ wth, const unsigned short* __restrict__ wtl,
    const float* __restrict__ bo, float* __restrict__ out)
{
    constexpr int AH = 0, BH = 16384, BL = 32768;
    __shared__ __align__(16) unsigned char smem[49152];

    const int tid = threadIdx.x, lane = tid & 63, w = tid >> 6;
    const int wm = w >> 1, wn = w & 1;
    const int c = lane & 31, hi = lane >> 5;
    const int m0 = blockIdx.y * 128, n0 = blockIdx.x * 128;

    const unsigned char* ah_base = (const unsigned char*)cnh;
    const unsigned char* bth = (const unsigned char*)wth;
    const unsigned char* btl = (const unsigned char*)wtl;

    int rr[4], gg[4], dd[4];
#pragma unroll
    for (int i = 0; i < 4; ++i) {
        int G = tid + 256 * i;
        rr[i] = G >> 3; gg[i] = G & 7;
        dd[i] = rr[i] * 128 + ((gg[i] ^ (rr[i] & 7)) * 16);
    }

    uint4v sah[4], sbh[4], sbl[4];
    auto loads = [&](int kt) {
        const int kb = kt * 128;
#pragma unroll
        for (int i = 0; i < 4; ++i) {
            const size_t arow = (size_t)(m0 + rr[i]) * 1024 + kb + gg[i] * 16;
            const size_t brow = (size_t)(n0 + rr[i]) * 1024 + kb + gg[i] * 16;
            sah[i] = *(const uint4v*)(ah_base + arow);
            sbh[i] = *(const uint4v*)(bth + brow);
            sbl[i] = *(const uint4v*)(btl + brow);
        }
    };
    auto writes = [&]() {
#pragma unroll
        for (int i = 0; i < 4; ++i) {
            *(uint4v*)(smem + AH + dd[i]) = sah[i];
            *(uint4v*)(smem + BH + dd[i]) = sbh[i];
            *(uint4v*)(smem + BL + dd[i]) = sbl[i];
        }
    };

    f32x16v acc[2][2];
#pragma unroll
    for (int a = 0; a < 2; ++a)
#pragma unroll
        for (int bq2 = 0; bq2 < 2; ++bq2)
#pragma unroll
            for (int r = 0; r < 16; ++r) acc[a][bq2][r] = 0.f;

    loads(0);
    for (int kt = 0; kt < NHD / 64; ++kt) {
        __syncthreads();
        writes();
        if (kt + 1 < NHD / 64) loads(kt + 1);
        __syncthreads();
#pragma unroll
        for (int ks = 0; ks < 4; ++ks) {
            short8v afh[2], bfh[2], bfl[2];
#pragma unroll
            for (int ms = 0; ms < 2; ++ms) {
                const int row = wm * 64 + ms * 32 + c;
                const int gb = row * 128 + (((2 * ks + hi) ^ (c & 7)) * 16);
                afh[ms] = *(const short8v*)(smem + AH + gb);
            }
#pragma unroll
            for (int ns = 0; ns < 2; ++ns) {
                const int row = wn * 64 + ns * 32 + c;
                const int gb = row * 128 + (((2 * ks + hi) ^ (c & 7)) * 16);
                bfh[ns] = *(const short8v*)(smem + BH + gb);
                bfl[ns] = *(const short8v*)(smem + BL + gb);
            }
#pragma unroll
            for (int ms = 0; ms < 2; ++ms)
#pragma unroll
                for (int ns = 0; ns < 2; ++ns) {
                    acc[ms][ns] = MFMA32(afh[ms], bfh[ns], acc[ms][ns]);
                    acc[ms][ns] = MFMA32(afh[ms], bfl[ns], acc[ms][ns]);
                }
        }
    }

#pragma unroll
    for (int ns = 0; ns < 2; ++ns) {
        const int n = n0 + wn * 64 + ns * 32 + c;
        const float bv4 = bo[n];
#pragma unroll
        for (int ms = 0; ms < 2; ++ms)
#pragma unroll
            for (int r = 0; r < 16; ++r) {
                const int m = m0 + wm * 64 + ms * 32 + (r & 3) + 8 * (r >> 2) + 4 * hi;
                out[(size_t)m * ND + n] = acc[ms][ns][r] + bv4;
            }
    }
}

// ---------------------------------------------------------------------------
extern "C" void kernel_launch(void* const* d_in, const int* in_sizes, int n_in,
                              void* d_out, int out_size, void* d_ws, size_t ws_size,
                              hipStream_t stream) {
    const float* Q    = (const float*)d_in[0];
    const float* mask = (const float*)d_in[1];
    const float* Wq   = (const float*)d_in[2];
    const float* bq   = (const float*)d_in[3];
    const float* Wk   = (const float*)d_in[4];
    const float* bk   = (const float*)d_in[5];
    const float* Wv   = (const float*)d_in[6];
    const float* bv   = (const float*)d_in[7];
    const float* Wo   = (const float*)d_in[8];
    const float* bo   = (const float*)d_in[9];

    unsigned char* W = (unsigned char*)d_ws;
    constexpr size_t MB = 1048576;
    // live-range-audited layout (no read/write overlap within any kernel):
    unsigned short* xh   = (unsigned short*)(W + 0);         // split_x .. proj_qkv
    unsigned short* xl   = (unsigned short*)(W + 8 * MB);    // split_x .. proj_qkv
    unsigned short* wtH  = (unsigned short*)(W + 16 * MB);   // split_wT .. proj_out
    unsigned short* wtL  = (unsigned short*)(W + 18 * MB);
    unsigned short* qh   = (unsigned short*)(W + 20 * MB);   // proj_qkv .. attn
    unsigned short* ql   = (unsigned short*)(W + 28 * MB);
    unsigned short* kh   = (unsigned short*)(W + 36 * MB);
    unsigned short* kl   = (unsigned short*)(W + 44 * MB);
    unsigned short* vh   = (unsigned short*)(W + 52 * MB);   // proj_qkv .. vt_convert
    unsigned short* vth  = (unsigned short*)(W + 0);         // vt_convert .. attn (over xh)
    unsigned short* cth  = (unsigned short*)(W + 8 * MB);    // attn .. ctx_split (over xl)
    unsigned short* cnh  = (unsigned short*)(W + 20 * MB);   // ctx_split .. proj_out (over qh)

    split_x<<<NM * ND / (256 * 16), 256, 0, stream>>>(Q, xh, xl);
    split_wT<<<dim3(8, 8, 4), 256, 0, stream>>>(Wq, Wk, Wv, Wo, wtH, wtL);

    proj_qkv_mfma<<<dim3(NHD / 128, NM / 128, 3), 256, 0, stream>>>(
        xh, xl, wtH, wtL, bq, bk, bv, qh, ql, kh, kl, vh);

    vt_convert<<<dim3(NS / 64, NB * NH), 256, 0, stream>>>(vh, vth);

    attn<<<512, 256, 0, stream>>>(qh, ql, kh, kl, vth, mask, cth);

    ctx_split<<<dim3(NS / 64, NB * NH), 256, 0, stream>>>(cth, cnh);

    proj_out_mfma<<<dim3(ND / 128, NM / 128), 256, 0, stream>>>(
        cnh, wtH + (size_t)3 * ND * ND, wtL + (size_t)3 * ND * ND,
        bo, (float*)d_out);
}